// Round 1
// baseline (1191.635 us; speedup 1.0000x reference)
//
#include <hip/hip_runtime.h>

// Problem constants
#define BB 8
#define LL 1024
#define DM 256
#define NH 8
#define DI 512
#define DS 16
#define DC 4
#define DR 16

// ---------------------------------------------------------------------------
// K1: embed  acc = accele @ acc_w.T + acc_b ; ang likewise
// grid 8192 blocks x 256 threads; thread d computes both outputs for its row
// ---------------------------------------------------------------------------
__global__ __launch_bounds__(256) void embed_k(
    const float* __restrict__ accele, const float* __restrict__ angle,
    const float* __restrict__ acc_w, const float* __restrict__ acc_b,
    const float* __restrict__ ang_w, const float* __restrict__ ang_b,
    float* __restrict__ accE, float* __restrict__ angE)
{
    const int row = blockIdx.x;            // b*1024 + l
    const int d = threadIdx.x;             // 0..255
    const float* a_in = accele + (size_t)row * 12;
    const float* g_in = angle + (size_t)row * 12;
    float sa = acc_b[d], sg = ang_b[d];
    #pragma unroll
    for (int j = 0; j < 12; ++j) {
        sa = fmaf(a_in[j], acc_w[d * 12 + j], sa);
        sg = fmaf(g_in[j], ang_w[d * 12 + j], sg);
    }
    accE[(size_t)row * DM + d] = sa;
    angE[(size_t)row * DM + d] = sg;
}

// ---------------------------------------------------------------------------
// Generic NT fp32 GEMM: C[m,n] = sum_k A[m,k] * W[n,k] (+ epilogue)
// 64x64 tile, BK=16, 256 threads, 4x4 per thread. M,N mult of 64; K mult of 16.
// EPI 0: C0[m*N+n] = v
// EPI 1: split n<512 -> C0 (xi), else C1 (z)    (N==1024)
// EPI 2: C0[m*N+n] = v + bias[n]
// EPI 3: v += bias[n]; scatter to out(8,1024,768)  (N==256, M==24576)
// ---------------------------------------------------------------------------
template<int EPI>
__global__ __launch_bounds__(256) void gemm_nt(
    const float* __restrict__ A, const float* __restrict__ W,
    const float* __restrict__ bias,
    float* __restrict__ C0, float* __restrict__ C1,
    int M, int N, int K)
{
    __shared__ float As[16][64];
    __shared__ float Ws[16][64];
    const int tid = threadIdx.x;
    const int tx = tid & 15;
    const int ty = tid >> 4;
    const int m0 = blockIdx.y * 64;
    const int n0 = blockIdx.x * 64;
    const int lr = tid >> 2;           // 0..63 tile row
    const int lk = (tid & 3) << 2;     // 0,4,8,12
    const float* Ag = A + (size_t)(m0 + lr) * K + lk;
    const float* Wg = W + (size_t)(n0 + lr) * K + lk;
    float acc[4][4];
    #pragma unroll
    for (int i = 0; i < 4; ++i)
        #pragma unroll
        for (int j = 0; j < 4; ++j) acc[i][j] = 0.f;

    for (int k0 = 0; k0 < K; k0 += 16) {
        float4 a4 = *(const float4*)(Ag + k0);
        float4 w4 = *(const float4*)(Wg + k0);
        __syncthreads();
        As[lk + 0][lr] = a4.x; As[lk + 1][lr] = a4.y;
        As[lk + 2][lr] = a4.z; As[lk + 3][lr] = a4.w;
        Ws[lk + 0][lr] = w4.x; Ws[lk + 1][lr] = w4.y;
        Ws[lk + 2][lr] = w4.z; Ws[lk + 3][lr] = w4.w;
        __syncthreads();
        #pragma unroll
        for (int k = 0; k < 16; ++k) {
            float4 av = *(const float4*)&As[k][ty << 2];
            float4 wv = *(const float4*)&Ws[k][tx << 2];
            float a[4] = {av.x, av.y, av.z, av.w};
            float w[4] = {wv.x, wv.y, wv.z, wv.w};
            #pragma unroll
            for (int i = 0; i < 4; ++i)
                #pragma unroll
                for (int j = 0; j < 4; ++j)
                    acc[i][j] = fmaf(a[i], w[j], acc[i][j]);
        }
    }

    #pragma unroll
    for (int i = 0; i < 4; ++i) {
        const int m = m0 + (ty << 2) + i;
        #pragma unroll
        for (int j = 0; j < 4; ++j) {
            const int n = n0 + (tx << 2) + j;
            float v = acc[i][j];
            if (EPI == 0) {
                C0[(size_t)m * N + n] = v;
            } else if (EPI == 1) {
                if (n < 512) C0[(size_t)m * 512 + n] = v;
                else         C1[(size_t)m * 512 + (n - 512)] = v;
            } else if (EPI == 2) {
                C0[(size_t)m * N + n] = v + bias[n];
            } else {
                v += bias[n];
                const int b = m / 3072;
                const int pos = m - b * 3072;
                const int seg = pos >> 10;
                const int l = pos & 1023;
                C0[(size_t)((b << 10) + l) * 768 + seg * 256 + n] = v;
            }
        }
    }
}

// ---------------------------------------------------------------------------
// K3: depthwise causal conv(4) + bias + SiLU.  One thread per (b,l,d).
// ---------------------------------------------------------------------------
__global__ __launch_bounds__(256) void conv_silu_k(
    const float* __restrict__ xi, const float* __restrict__ cw,
    const float* __restrict__ cb, float* __restrict__ xc)
{
    const size_t idx = (size_t)blockIdx.x * 256 + threadIdx.x; // < 8*1024*512
    const int d = (int)(idx & 511);
    const int l = (int)((idx >> 9) & 1023);
    const float4 w4 = ((const float4*)cw)[d];
    const float* p = xi + idx;
    float s = cb[d];
    s = fmaf((l >= 3 ? p[-3 * 512] : 0.f), w4.x, s);
    s = fmaf((l >= 2 ? p[-2 * 512] : 0.f), w4.y, s);
    s = fmaf((l >= 1 ? p[-1 * 512] : 0.f), w4.z, s);
    s = fmaf(p[0], w4.w, s);
    xc[idx] = s / (1.f + __expf(-s));   // silu
}

// ---------------------------------------------------------------------------
// K4: x_proj  dbl[row, j<48] = xc[row,:] . x_proj_w[j,:]   (K=512)
// one wave per row; row staged in LDS; lanes 48..63 idle
// ---------------------------------------------------------------------------
__global__ __launch_bounds__(64) void xproj_k(
    const float* __restrict__ xc, const float* __restrict__ w,
    float* __restrict__ dbl)
{
    __shared__ float4 rb[128];
    const int row = blockIdx.x;
    const float4* src = (const float4*)(xc + (size_t)row * DI);
    rb[threadIdx.x] = src[threadIdx.x];
    rb[threadIdx.x + 64] = src[threadIdx.x + 64];
    __syncthreads();
    const int j = threadIdx.x;
    if (j < 48) {
        const float4* wr = (const float4*)(w + (size_t)j * DI);
        float s = 0.f;
        #pragma unroll 8
        for (int k = 0; k < 128; ++k) {
            float4 a = rb[k]; float4 b = wr[k];
            s = fmaf(a.x, b.x, s); s = fmaf(a.y, b.y, s);
            s = fmaf(a.z, b.z, s); s = fmaf(a.w, b.w, s);
        }
        dbl[(size_t)row * 48 + j] = s;
    }
}

// ---------------------------------------------------------------------------
// K5: delta[row,d] = softplus(dbl[row,:16] . dt_w[d,:] + dt_b[d])
// ---------------------------------------------------------------------------
__global__ __launch_bounds__(256) void delta_k(
    const float* __restrict__ dbl, const float* __restrict__ dtw,
    const float* __restrict__ dtb, float* __restrict__ dlt)
{
    const size_t idx = (size_t)blockIdx.x * 256 + threadIdx.x; // < 8192*512
    const int d = (int)(idx & 511);
    const size_t row = idx >> 9;
    const float4* dr = (const float4*)(dbl + row * 48);
    const float4* wr = (const float4*)(dtw + (size_t)d * 16);
    float s = dtb[d];
    #pragma unroll
    for (int r = 0; r < 4; ++r) {
        float4 a = dr[r]; float4 b = wr[r];
        s = fmaf(a.x, b.x, s); s = fmaf(a.y, b.y, s);
        s = fmaf(a.z, b.z, s); s = fmaf(a.w, b.w, s);
    }
    dlt[idx] = (s > 20.f) ? s : log1pf(__expf(s));
}

// ---------------------------------------------------------------------------
// K6: selective scan + gate.  64 blocks x 64 threads; thread = one (b,d),
// h[16] in registers, explicit next-step prefetch.
// yg[row,d] = (y + u*Dp[d]) * silu(z[row,d])
// ---------------------------------------------------------------------------
__global__ __launch_bounds__(64) void scan_k(
    const float* __restrict__ dlt, const float* __restrict__ xc,
    const float* __restrict__ dbl, const float* __restrict__ zb,
    const float* __restrict__ A_log, const float* __restrict__ Dpp,
    float* __restrict__ yg)
{
    const int b = blockIdx.x >> 3;
    const int d = ((blockIdx.x & 7) << 6) + threadIdx.x;
    float A[16];
    #pragma unroll
    for (int s = 0; s < 16; ++s) A[s] = -__expf(A_log[(size_t)d * 16 + s]);
    const float Dpv = Dpp[d];
    float h[16];
    #pragma unroll
    for (int s = 0; s < 16; ++s) h[s] = 0.f;

    const size_t rowbase = (size_t)b * LL;
    // preload step 0
    size_t row = rowbase;
    float cd = dlt[row * DI + d];
    float cu = xc[row * DI + d];
    float cz = zb[row * DI + d];
    float Bc[16], Cc[16];
    #pragma unroll
    for (int s = 0; s < 16; ++s) {
        Bc[s] = dbl[row * 48 + 16 + s];
        Cc[s] = dbl[row * 48 + 32 + s];
    }

    for (int l = 0; l < LL; ++l) {
        const size_t nrow = rowbase + (l + 1 < LL ? l + 1 : l);
        // prefetch next step
        const float nd = dlt[nrow * DI + d];
        const float nu = xc[nrow * DI + d];
        const float nz = zb[nrow * DI + d];
        float nB[16], nC[16];
        #pragma unroll
        for (int s = 0; s < 16; ++s) {
            nB[s] = dbl[nrow * 48 + 16 + s];
            nC[s] = dbl[nrow * 48 + 32 + s];
        }
        // compute current step
        const float du = cd * cu;
        float y = 0.f;
        #pragma unroll
        for (int s = 0; s < 16; ++s) {
            const float a = __expf(cd * A[s]);
            h[s] = fmaf(h[s], a, du * Bc[s]);
            y = fmaf(h[s], Cc[s], y);
        }
        const float sig = 1.f / (1.f + __expf(-cz));
        yg[(rowbase + l) * DI + d] = (y + cu * Dpv) * (cz * sig);
        // rotate
        cd = nd; cu = nu; cz = nz;
        #pragma unroll
        for (int s = 0; s < 16; ++s) { Bc[s] = nB[s]; Cc[s] = nC[s]; }
    }
}

// ---------------------------------------------------------------------------
// K8: LayerNorm of the three segments into hcat (B, 3L, 256)
// one wave per row; lane handles 4 channels
// ---------------------------------------------------------------------------
__global__ __launch_bounds__(64) void ln_concat_k(
    const float* __restrict__ x, const float* __restrict__ mo,
    const float* __restrict__ angE,
    const float* __restrict__ nw, const float* __restrict__ nb,
    const float* __restrict__ naw, const float* __restrict__ nab,
    const float* __restrict__ ngw, const float* __restrict__ ngb,
    float* __restrict__ hcat)
{
    const int rowo = blockIdx.x;              // 0..24575
    const int b = rowo / 3072;
    const int pos = rowo - b * 3072;
    const int seg = pos >> 10;
    const int l = pos & 1023;
    const size_t srow = (size_t)b * LL + l;
    const float* src; const float* w; const float* bias;
    if (seg == 0)      { src = x    + srow * DM; w = nw;  bias = nb;  }
    else if (seg == 1) { src = mo   + srow * DM; w = naw; bias = nab; }
    else               { src = angE + srow * DM; w = ngw; bias = ngb; }

    const int lane = threadIdx.x;
    float4 v = *(const float4*)(src + lane * 4);
    float s  = v.x + v.y + v.z + v.w;
    float s2 = v.x * v.x + v.y * v.y + v.z * v.z + v.w * v.w;
    #pragma unroll
    for (int off = 32; off > 0; off >>= 1) {
        s  += __shfl_down(s, off);
        s2 += __shfl_down(s2, off);
    }
    s = __shfl(s, 0); s2 = __shfl(s2, 0);
    const float mean = s * (1.f / DM);
    const float var = s2 * (1.f / DM) - mean * mean;
    const float inv = rsqrtf(var + 1e-5f);
    float4 wv = *(const float4*)(w + lane * 4);
    float4 bv = *(const float4*)(bias + lane * 4);
    float4 o;
    o.x = (v.x - mean) * inv * wv.x + bv.x;
    o.y = (v.y - mean) * inv * wv.y + bv.y;
    o.z = (v.z - mean) * inv * wv.z + bv.z;
    o.w = (v.w - mean) * inv * wv.w + bv.w;
    *(float4*)(hcat + (size_t)rowo * DM + lane * 4) = o;
}

// ---------------------------------------------------------------------------
// K10: attention over S=8 (batch axis).  One wave per n; lane = (head, s).
// ---------------------------------------------------------------------------
__global__ __launch_bounds__(64) void attn_k(
    const float* __restrict__ qkv, float* __restrict__ atto)
{
    const int n = blockIdx.x;                 // 0..3071
    const int hd = threadIdx.x >> 3;          // head
    const int s = threadIdx.x & 7;
    const float scale = 0.17677669529663687f; // 1/sqrt(32)

    float q[32];
    {
        const float4* qp = (const float4*)(qkv + ((size_t)(s * 3072 + n)) * 768 + hd * 32);
        #pragma unroll
        for (int i = 0; i < 8; ++i) {
            float4 t = qp[i];
            q[i * 4 + 0] = t.x; q[i * 4 + 1] = t.y; q[i * 4 + 2] = t.z; q[i * 4 + 3] = t.w;
        }
    }
    float sc[8];
    #pragma unroll
    for (int t = 0; t < 8; ++t) {
        const float4* kp = (const float4*)(qkv + ((size_t)(t * 3072 + n)) * 768 + 256 + hd * 32);
        float dot = 0.f;
        #pragma unroll
        for (int i = 0; i < 8; ++i) {
            float4 kv = kp[i];
            dot = fmaf(q[i * 4 + 0], kv.x, dot);
            dot = fmaf(q[i * 4 + 1], kv.y, dot);
            dot = fmaf(q[i * 4 + 2], kv.z, dot);
            dot = fmaf(q[i * 4 + 3], kv.w, dot);
        }
        sc[t] = dot * scale;
    }
    float mx = sc[0];
    #pragma unroll
    for (int t = 1; t < 8; ++t) mx = fmaxf(mx, sc[t]);
    float se = 0.f;
    #pragma unroll
    for (int t = 0; t < 8; ++t) { sc[t] = __expf(sc[t] - mx); se += sc[t]; }
    const float inv = 1.f / se;

    float o[32];
    #pragma unroll
    for (int i = 0; i < 32; ++i) o[i] = 0.f;
    #pragma unroll
    for (int t = 0; t < 8; ++t) {
        const float4* vp = (const float4*)(qkv + ((size_t)(t * 3072 + n)) * 768 + 512 + hd * 32);
        const float wgt = sc[t] * inv;
        #pragma unroll
        for (int i = 0; i < 8; ++i) {
            float4 vv = vp[i];
            o[i * 4 + 0] = fmaf(wgt, vv.x, o[i * 4 + 0]);
            o[i * 4 + 1] = fmaf(wgt, vv.y, o[i * 4 + 1]);
            o[i * 4 + 2] = fmaf(wgt, vv.z, o[i * 4 + 2]);
            o[i * 4 + 3] = fmaf(wgt, vv.w, o[i * 4 + 3]);
        }
    }
    float4* op = (float4*)(atto + ((size_t)(s * 3072 + n)) * 256 + hd * 32);
    #pragma unroll
    for (int i = 0; i < 8; ++i) {
        float4 t; t.x = o[i * 4 + 0]; t.y = o[i * 4 + 1]; t.z = o[i * 4 + 2]; t.w = o[i * 4 + 3];
        op[i] = t;
    }
}

// ---------------------------------------------------------------------------
extern "C" void kernel_launch(void* const* d_in, const int* in_sizes, int n_in,
                              void* d_out, int out_size, void* d_ws, size_t ws_size,
                              hipStream_t stream) {
    const float* x         = (const float*)d_in[0];
    const float* accele    = (const float*)d_in[1];
    const float* angle     = (const float*)d_in[2];
    const float* acc_w     = (const float*)d_in[3];
    const float* acc_b     = (const float*)d_in[4];
    const float* ang_w     = (const float*)d_in[5];
    const float* ang_b     = (const float*)d_in[6];
    const float* in_proj_w = (const float*)d_in[7];
    const float* conv_w    = (const float*)d_in[8];
    const float* conv_b    = (const float*)d_in[9];
    const float* x_proj_w  = (const float*)d_in[10];
    const float* dt_proj_w = (const float*)d_in[11];
    const float* dt_proj_b = (const float*)d_in[12];
    const float* A_log     = (const float*)d_in[13];
    const float* Dp        = (const float*)d_in[14];
    const float* out_proj_w= (const float*)d_in[15];
    const float* norm_w    = (const float*)d_in[16];
    const float* norm_b    = (const float*)d_in[17];
    const float* norm_acc_w= (const float*)d_in[18];
    const float* norm_acc_b= (const float*)d_in[19];
    const float* norm_ang_w= (const float*)d_in[20];
    const float* norm_ang_b= (const float*)d_in[21];
    const float* attn_in_w = (const float*)d_in[22];
    const float* attn_in_b = (const float*)d_in[23];
    const float* attn_out_w= (const float*)d_in[24];
    const float* attn_out_b= (const float*)d_in[25];

    float* ws = (float*)d_ws;
    // workspace layout (floats)
    float* accE = ws;                    //  2,097,152
    float* angE = ws + 2097152;          //  2,097,152
    float* xi   = ws + 4194304;          //  4,194,304
    float* zb   = ws + 8388608;          //  4,194,304
    float* xc   = ws + 12582912;         //  4,194,304
    float* dblb = ws + 16777216;         //    393,216
    float* dltb = ws + 17170432;         //  4,194,304
    float* yg   = ws + 21364736;         //  4,194,304
    float* mo   = ws + 25559040;         //  2,097,152
    float* hcat = ws + 27656192;         //  6,291,456
    float* atto = ws + 33947648;         //  6,291,456
    float* qkvb = ws;                    // alias: 18,874,368 < 27,656,192 (mamba bufs dead)

    // 1. embeds
    embed_k<<<dim3(BB * LL), dim3(256), 0, stream>>>(
        accele, angle, acc_w, acc_b, ang_w, ang_b, accE, angE);

    // 2. in_proj: xz = accE @ in_proj_w.T  -> split xi | z
    gemm_nt<1><<<dim3(1024 / 64, (BB * LL) / 64), dim3(256), 0, stream>>>(
        accE, in_proj_w, nullptr, xi, zb, BB * LL, 1024, DM);

    // 3. causal depthwise conv + SiLU
    conv_silu_k<<<dim3((BB * LL * DI) / 256), dim3(256), 0, stream>>>(
        xi, conv_w, conv_b, xc);

    // 4. x_proj -> dbl (dt|B|C)
    xproj_k<<<dim3(BB * LL), dim3(64), 0, stream>>>(xc, x_proj_w, dblb);

    // 5. delta = softplus(dt @ dt_proj_w.T + dt_proj_b)
    delta_k<<<dim3((BB * LL * DI) / 256), dim3(256), 0, stream>>>(
        dblb, dt_proj_w, dt_proj_b, dltb);

    // 6. selective scan + gate
    scan_k<<<dim3(64), dim3(64), 0, stream>>>(
        dltb, xc, dblb, zb, A_log, Dp, yg);

    // 7. out_proj -> mamba output
    gemm_nt<0><<<dim3(DM / 64, (BB * LL) / 64), dim3(256), 0, stream>>>(
        yg, out_proj_w, nullptr, mo, nullptr, BB * LL, DM, DI);

    // 8. 3x LayerNorm -> hcat (B, 3L, 256)
    ln_concat_k<<<dim3(BB * 3 * LL), dim3(64), 0, stream>>>(
        x, mo, angE, norm_w, norm_b, norm_acc_w, norm_acc_b,
        norm_ang_w, norm_ang_b, hcat);

    // 9. qkv = hcat @ attn_in_w.T + attn_in_b
    gemm_nt<2><<<dim3(768 / 64, (BB * 3 * LL) / 64), dim3(256), 0, stream>>>(
        hcat, attn_in_w, attn_in_b, qkvb, nullptr, BB * 3 * LL, 768, DM);

    // 10. attention over S=8
    attn_k<<<dim3(3 * LL), dim3(64), 0, stream>>>(qkvb, atto);

    // 11. out-proj + bias + scatter into (8,1024,768) output
    gemm_nt<3><<<dim3(DM / 64, (BB * 3 * LL) / 64), dim3(256), 0, stream>>>(
        atto, attn_out_w, attn_out_b, (float*)d_out, nullptr, BB * 3 * LL, DM, DM);
}

// Round 2
// 622.646 us; speedup vs baseline: 1.9138x; 1.9138x over previous
//
#include <hip/hip_runtime.h>

// Problem constants
#define BB 8
#define LL 1024
#define DM 256
#define NH 8
#define DI 512
#define DS 16
#define DC 4
#define DR 16

// chunked-scan constants
#define CH 32   // number of chunks per sequence
#define CL 32   // steps per chunk (CH*CL == LL)

// ---------------------------------------------------------------------------
// K1: embed  acc = accele @ acc_w.T + acc_b ; ang likewise
// ---------------------------------------------------------------------------
__global__ __launch_bounds__(256) void embed_k(
    const float* __restrict__ accele, const float* __restrict__ angle,
    const float* __restrict__ acc_w, const float* __restrict__ acc_b,
    const float* __restrict__ ang_w, const float* __restrict__ ang_b,
    float* __restrict__ accE, float* __restrict__ angE)
{
    const int row = blockIdx.x;            // b*1024 + l
    const int d = threadIdx.x;             // 0..255
    const float* a_in = accele + (size_t)row * 12;
    const float* g_in = angle + (size_t)row * 12;
    float sa = acc_b[d], sg = ang_b[d];
    #pragma unroll
    for (int j = 0; j < 12; ++j) {
        sa = fmaf(a_in[j], acc_w[d * 12 + j], sa);
        sg = fmaf(g_in[j], ang_w[d * 12 + j], sg);
    }
    accE[(size_t)row * DM + d] = sa;
    angE[(size_t)row * DM + d] = sg;
}

// ---------------------------------------------------------------------------
// Generic NT fp32 GEMM: C[m,n] = sum_k A[m,k] * W[n,k] (+ epilogue)
// 64x64 tile, BK=16, 256 threads, 4x4 per thread.
// ---------------------------------------------------------------------------
template<int EPI>
__global__ __launch_bounds__(256) void gemm_nt(
    const float* __restrict__ A, const float* __restrict__ W,
    const float* __restrict__ bias,
    float* __restrict__ C0, float* __restrict__ C1,
    int M, int N, int K)
{
    __shared__ float As[16][64];
    __shared__ float Ws[16][64];
    const int tid = threadIdx.x;
    const int tx = tid & 15;
    const int ty = tid >> 4;
    const int m0 = blockIdx.y * 64;
    const int n0 = blockIdx.x * 64;
    const int lr = tid >> 2;           // 0..63 tile row
    const int lk = (tid & 3) << 2;     // 0,4,8,12
    const float* Ag = A + (size_t)(m0 + lr) * K + lk;
    const float* Wg = W + (size_t)(n0 + lr) * K + lk;
    float acc[4][4];
    #pragma unroll
    for (int i = 0; i < 4; ++i)
        #pragma unroll
        for (int j = 0; j < 4; ++j) acc[i][j] = 0.f;

    for (int k0 = 0; k0 < K; k0 += 16) {
        float4 a4 = *(const float4*)(Ag + k0);
        float4 w4 = *(const float4*)(Wg + k0);
        __syncthreads();
        As[lk + 0][lr] = a4.x; As[lk + 1][lr] = a4.y;
        As[lk + 2][lr] = a4.z; As[lk + 3][lr] = a4.w;
        Ws[lk + 0][lr] = w4.x; Ws[lk + 1][lr] = w4.y;
        Ws[lk + 2][lr] = w4.z; Ws[lk + 3][lr] = w4.w;
        __syncthreads();
        #pragma unroll
        for (int k = 0; k < 16; ++k) {
            float4 av = *(const float4*)&As[k][ty << 2];
            float4 wv = *(const float4*)&Ws[k][tx << 2];
            float a[4] = {av.x, av.y, av.z, av.w};
            float w[4] = {wv.x, wv.y, wv.z, wv.w};
            #pragma unroll
            for (int i = 0; i < 4; ++i)
                #pragma unroll
                for (int j = 0; j < 4; ++j)
                    acc[i][j] = fmaf(a[i], w[j], acc[i][j]);
        }
    }

    #pragma unroll
    for (int i = 0; i < 4; ++i) {
        const int m = m0 + (ty << 2) + i;
        #pragma unroll
        for (int j = 0; j < 4; ++j) {
            const int n = n0 + (tx << 2) + j;
            float v = acc[i][j];
            if (EPI == 0) {
                C0[(size_t)m * N + n] = v;
            } else if (EPI == 1) {
                if (n < 512) C0[(size_t)m * 512 + n] = v;
                else         C1[(size_t)m * 512 + (n - 512)] = v;
            } else if (EPI == 2) {
                C0[(size_t)m * N + n] = v + bias[n];
            } else {
                v += bias[n];
                const int b = m / 3072;
                const int pos = m - b * 3072;
                const int seg = pos >> 10;
                const int l = pos & 1023;
                C0[(size_t)((b << 10) + l) * 768 + seg * 256 + n] = v;
            }
        }
    }
}

// ---------------------------------------------------------------------------
// K3: depthwise causal conv(4) + bias + SiLU.
// ---------------------------------------------------------------------------
__global__ __launch_bounds__(256) void conv_silu_k(
    const float* __restrict__ xi, const float* __restrict__ cw,
    const float* __restrict__ cb, float* __restrict__ xc)
{
    const size_t idx = (size_t)blockIdx.x * 256 + threadIdx.x; // < 8*1024*512
    const int d = (int)(idx & 511);
    const int l = (int)((idx >> 9) & 1023);
    const float4 w4 = ((const float4*)cw)[d];
    const float* p = xi + idx;
    float s = cb[d];
    s = fmaf((l >= 3 ? p[-3 * 512] : 0.f), w4.x, s);
    s = fmaf((l >= 2 ? p[-2 * 512] : 0.f), w4.y, s);
    s = fmaf((l >= 1 ? p[-1 * 512] : 0.f), w4.z, s);
    s = fmaf(p[0], w4.w, s);
    xc[idx] = s / (1.f + __expf(-s));   // silu
}

// ---------------------------------------------------------------------------
// K4: x_proj  dbl[row, j<48] = xc[row,:] . x_proj_w[j,:]   (K=512)
// ---------------------------------------------------------------------------
__global__ __launch_bounds__(64) void xproj_k(
    const float* __restrict__ xc, const float* __restrict__ w,
    float* __restrict__ dbl)
{
    __shared__ float4 rb[128];
    const int row = blockIdx.x;
    const float4* src = (const float4*)(xc + (size_t)row * DI);
    rb[threadIdx.x] = src[threadIdx.x];
    rb[threadIdx.x + 64] = src[threadIdx.x + 64];
    __syncthreads();
    const int j = threadIdx.x;
    if (j < 48) {
        const float4* wr = (const float4*)(w + (size_t)j * DI);
        float s = 0.f;
        #pragma unroll 8
        for (int k = 0; k < 128; ++k) {
            float4 a = rb[k]; float4 b = wr[k];
            s = fmaf(a.x, b.x, s); s = fmaf(a.y, b.y, s);
            s = fmaf(a.z, b.z, s); s = fmaf(a.w, b.w, s);
        }
        dbl[(size_t)row * 48 + j] = s;
    }
}

// ---------------------------------------------------------------------------
// K5: delta[row,d] = softplus(dbl[row,:16] . dt_w[d,:] + dt_b[d])
// ---------------------------------------------------------------------------
__global__ __launch_bounds__(256) void delta_k(
    const float* __restrict__ dbl, const float* __restrict__ dtw,
    const float* __restrict__ dtb, float* __restrict__ dlt)
{
    const size_t idx = (size_t)blockIdx.x * 256 + threadIdx.x; // < 8192*512
    const int d = (int)(idx & 511);
    const size_t row = idx >> 9;
    const float4* dr = (const float4*)(dbl + row * 48);
    const float4* wr = (const float4*)(dtw + (size_t)d * 16);
    float s = dtb[d];
    #pragma unroll
    for (int r = 0; r < 4; ++r) {
        float4 a = dr[r]; float4 b = wr[r];
        s = fmaf(a.x, b.x, s); s = fmaf(a.y, b.y, s);
        s = fmaf(a.z, b.z, s); s = fmaf(a.w, b.w, s);
    }
    dlt[idx] = (s > 20.f) ? s : log1pf(__expf(s));
}

// ---------------------------------------------------------------------------
// Chunked selective scan.
// h_t = h_{t-1}*exp(delta_t*A) + delta_t*u_t*B_t  is linear in h, and the
// chunk-level decay is exp(A * sum(delta)).  3 passes:
//   scan1: per (b,d,chunk): scan chunk from h=0 -> h_local[16], dsum
//   scan2: sequential prefix over chunks (tiny): h_local -> h_in (in place)
//   scan3: rescan chunk from h_in, compute y, fuse gate, write yg
// hmid layout: [b][chunk][s][d]  (coalesced in d)
// ---------------------------------------------------------------------------
__global__ __launch_bounds__(512) void scan1_k(
    const float* __restrict__ dlt, const float* __restrict__ xc,
    const float* __restrict__ dbl, const float* __restrict__ A_log,
    float* __restrict__ hmid, float* __restrict__ dsums)
{
    __shared__ float Bs[CL][16];
    const int b = blockIdx.x >> 5;          // 0..7
    const int c = blockIdx.x & 31;          // chunk 0..31
    const int d = threadIdx.x;              // 0..511
    const size_t rowbase = (size_t)b * LL + (size_t)c * CL;
    {   // stage B for this chunk (512 threads cover 32*16 elems exactly)
        const int l = threadIdx.x >> 4, s = threadIdx.x & 15;
        Bs[l][s] = dbl[(rowbase + l) * 48 + 16 + s];
    }
    __syncthreads();
    float A[16];
    #pragma unroll
    for (int s = 0; s < 16; ++s) A[s] = -__expf(A_log[(size_t)d * 16 + s]);
    float h[16];
    #pragma unroll
    for (int s = 0; s < 16; ++s) h[s] = 0.f;
    float dsum = 0.f;
    #pragma unroll 4
    for (int l = 0; l < CL; ++l) {
        const size_t row = rowbase + l;
        const float dv = dlt[row * DI + d];
        const float uv = xc[row * DI + d];
        const float du = dv * uv;
        dsum += dv;
        #pragma unroll
        for (int s = 0; s < 16; ++s)
            h[s] = fmaf(h[s], __expf(dv * A[s]), du * Bs[l][s]);
    }
    const size_t base = (size_t)(b * CH + c) * 16 * DI + d;
    #pragma unroll
    for (int s = 0; s < 16; ++s) hmid[base + (size_t)s * DI] = h[s];
    dsums[(size_t)(b * CH + c) * DI + d] = dsum;
}

__global__ __launch_bounds__(64) void scan2_k(
    const float* __restrict__ A_log, float* __restrict__ hmid,
    const float* __restrict__ dsums)
{
    const int b = blockIdx.x >> 3;
    const int d = ((blockIdx.x & 7) << 6) + threadIdx.x;
    float A[16];
    #pragma unroll
    for (int s = 0; s < 16; ++s) A[s] = -__expf(A_log[(size_t)d * 16 + s]);
    float h[16];
    #pragma unroll
    for (int s = 0; s < 16; ++s) h[s] = 0.f;

    // prefetch chunk 0
    size_t base = (size_t)(b * CH) * 16 * DI + d;
    float tmp[16];
    #pragma unroll
    for (int s = 0; s < 16; ++s) tmp[s] = hmid[base + (size_t)s * DI];
    float ds = dsums[(size_t)(b * CH) * DI + d];

    for (int c = 0; c < CH; ++c) {
        // prefetch next chunk
        const int cn = (c + 1 < CH) ? c + 1 : c;
        const size_t nbase = (size_t)(b * CH + cn) * 16 * DI + d;
        float ntmp[16];
        #pragma unroll
        for (int s = 0; s < 16; ++s) ntmp[s] = hmid[nbase + (size_t)s * DI];
        const float nds = dsums[(size_t)(b * CH + cn) * DI + d];
        // write h_in for chunk c, advance h
        #pragma unroll
        for (int s = 0; s < 16; ++s) {
            const float hin = h[s];
            hmid[base + (size_t)s * DI] = hin;
            h[s] = fmaf(hin, __expf(A[s] * ds), tmp[s]);
        }
        base = nbase; ds = nds;
        #pragma unroll
        for (int s = 0; s < 16; ++s) tmp[s] = ntmp[s];
    }
}

__global__ __launch_bounds__(512) void scan3_k(
    const float* __restrict__ dlt, const float* __restrict__ xc,
    const float* __restrict__ dbl, const float* __restrict__ zb,
    const float* __restrict__ A_log, const float* __restrict__ Dpp,
    const float* __restrict__ hmid, float* __restrict__ yg)
{
    __shared__ float Bs[CL][16];
    __shared__ float Cs[CL][16];
    const int b = blockIdx.x >> 5;
    const int c = blockIdx.x & 31;
    const int d = threadIdx.x;
    const size_t rowbase = (size_t)b * LL + (size_t)c * CL;
    {
        const int l = threadIdx.x >> 4, s = threadIdx.x & 15;
        Bs[l][s] = dbl[(rowbase + l) * 48 + 16 + s];
        Cs[l][s] = dbl[(rowbase + l) * 48 + 32 + s];
    }
    __syncthreads();
    float A[16];
    #pragma unroll
    for (int s = 0; s < 16; ++s) A[s] = -__expf(A_log[(size_t)d * 16 + s]);
    float h[16];
    const size_t base = (size_t)(b * CH + c) * 16 * DI + d;
    #pragma unroll
    for (int s = 0; s < 16; ++s) h[s] = hmid[base + (size_t)s * DI];
    const float Dpv = Dpp[d];

    #pragma unroll 4
    for (int l = 0; l < CL; ++l) {
        const size_t row = rowbase + l;
        const float dv = dlt[row * DI + d];
        const float uv = xc[row * DI + d];
        const float zv = zb[row * DI + d];
        const float du = dv * uv;
        float y = 0.f;
        #pragma unroll
        for (int s = 0; s < 16; ++s) {
            h[s] = fmaf(h[s], __expf(dv * A[s]), du * Bs[l][s]);
            y = fmaf(h[s], Cs[l][s], y);
        }
        const float sig = 1.f / (1.f + __expf(-zv));
        yg[row * DI + d] = (y + uv * Dpv) * (zv * sig);
    }
}

// ---------------------------------------------------------------------------
// K8: LayerNorm of the three segments into hcat (B, 3L, 256)
// ---------------------------------------------------------------------------
__global__ __launch_bounds__(64) void ln_concat_k(
    const float* __restrict__ x, const float* __restrict__ mo,
    const float* __restrict__ angE,
    const float* __restrict__ nw, const float* __restrict__ nb,
    const float* __restrict__ naw, const float* __restrict__ nab,
    const float* __restrict__ ngw, const float* __restrict__ ngb,
    float* __restrict__ hcat)
{
    const int rowo = blockIdx.x;              // 0..24575
    const int b = rowo / 3072;
    const int pos = rowo - b * 3072;
    const int seg = pos >> 10;
    const int l = pos & 1023;
    const size_t srow = (size_t)b * LL + l;
    const float* src; const float* w; const float* bias;
    if (seg == 0)      { src = x    + srow * DM; w = nw;  bias = nb;  }
    else if (seg == 1) { src = mo   + srow * DM; w = naw; bias = nab; }
    else               { src = angE + srow * DM; w = ngw; bias = ngb; }

    const int lane = threadIdx.x;
    float4 v = *(const float4*)(src + lane * 4);
    float s  = v.x + v.y + v.z + v.w;
    float s2 = v.x * v.x + v.y * v.y + v.z * v.z + v.w * v.w;
    #pragma unroll
    for (int off = 32; off > 0; off >>= 1) {
        s  += __shfl_down(s, off);
        s2 += __shfl_down(s2, off);
    }
    s = __shfl(s, 0); s2 = __shfl(s2, 0);
    const float mean = s * (1.f / DM);
    const float var = s2 * (1.f / DM) - mean * mean;
    const float inv = rsqrtf(var + 1e-5f);
    float4 wv = *(const float4*)(w + lane * 4);
    float4 bv = *(const float4*)(bias + lane * 4);
    float4 o;
    o.x = (v.x - mean) * inv * wv.x + bv.x;
    o.y = (v.y - mean) * inv * wv.y + bv.y;
    o.z = (v.z - mean) * inv * wv.z + bv.z;
    o.w = (v.w - mean) * inv * wv.w + bv.w;
    *(float4*)(hcat + (size_t)rowo * DM + lane * 4) = o;
}

// ---------------------------------------------------------------------------
// K10: attention over S=8 (batch axis).  One wave per n; lane = (head, s).
// ---------------------------------------------------------------------------
__global__ __launch_bounds__(64) void attn_k(
    const float* __restrict__ qkv, float* __restrict__ atto)
{
    const int n = blockIdx.x;                 // 0..3071
    const int hd = threadIdx.x >> 3;          // head
    const int s = threadIdx.x & 7;
    const float scale = 0.17677669529663687f; // 1/sqrt(32)

    float q[32];
    {
        const float4* qp = (const float4*)(qkv + ((size_t)(s * 3072 + n)) * 768 + hd * 32);
        #pragma unroll
        for (int i = 0; i < 8; ++i) {
            float4 t = qp[i];
            q[i * 4 + 0] = t.x; q[i * 4 + 1] = t.y; q[i * 4 + 2] = t.z; q[i * 4 + 3] = t.w;
        }
    }
    float sc[8];
    #pragma unroll
    for (int t = 0; t < 8; ++t) {
        const float4* kp = (const float4*)(qkv + ((size_t)(t * 3072 + n)) * 768 + 256 + hd * 32);
        float dot = 0.f;
        #pragma unroll
        for (int i = 0; i < 8; ++i) {
            float4 kv = kp[i];
            dot = fmaf(q[i * 4 + 0], kv.x, dot);
            dot = fmaf(q[i * 4 + 1], kv.y, dot);
            dot = fmaf(q[i * 4 + 2], kv.z, dot);
            dot = fmaf(q[i * 4 + 3], kv.w, dot);
        }
        sc[t] = dot * scale;
    }
    float mx = sc[0];
    #pragma unroll
    for (int t = 1; t < 8; ++t) mx = fmaxf(mx, sc[t]);
    float se = 0.f;
    #pragma unroll
    for (int t = 0; t < 8; ++t) { sc[t] = __expf(sc[t] - mx); se += sc[t]; }
    const float inv = 1.f / se;

    float o[32];
    #pragma unroll
    for (int i = 0; i < 32; ++i) o[i] = 0.f;
    #pragma unroll
    for (int t = 0; t < 8; ++t) {
        const float4* vp = (const float4*)(qkv + ((size_t)(t * 3072 + n)) * 768 + 512 + hd * 32);
        const float wgt = sc[t] * inv;
        #pragma unroll
        for (int i = 0; i < 8; ++i) {
            float4 vv = vp[i];
            o[i * 4 + 0] = fmaf(wgt, vv.x, o[i * 4 + 0]);
            o[i * 4 + 1] = fmaf(wgt, vv.y, o[i * 4 + 1]);
            o[i * 4 + 2] = fmaf(wgt, vv.z, o[i * 4 + 2]);
            o[i * 4 + 3] = fmaf(wgt, vv.w, o[i * 4 + 3]);
        }
    }
    float4* op = (float4*)(atto + ((size_t)(s * 3072 + n)) * 256 + hd * 32);
    #pragma unroll
    for (int i = 0; i < 8; ++i) {
        float4 t; t.x = o[i * 4 + 0]; t.y = o[i * 4 + 1]; t.z = o[i * 4 + 2]; t.w = o[i * 4 + 3];
        op[i] = t;
    }
}

// ---------------------------------------------------------------------------
extern "C" void kernel_launch(void* const* d_in, const int* in_sizes, int n_in,
                              void* d_out, int out_size, void* d_ws, size_t ws_size,
                              hipStream_t stream) {
    const float* x         = (const float*)d_in[0];
    const float* accele    = (const float*)d_in[1];
    const float* angle     = (const float*)d_in[2];
    const float* acc_w     = (const float*)d_in[3];
    const float* acc_b     = (const float*)d_in[4];
    const float* ang_w     = (const float*)d_in[5];
    const float* ang_b     = (const float*)d_in[6];
    const float* in_proj_w = (const float*)d_in[7];
    const float* conv_w    = (const float*)d_in[8];
    const float* conv_b    = (const float*)d_in[9];
    const float* x_proj_w  = (const float*)d_in[10];
    const float* dt_proj_w = (const float*)d_in[11];
    const float* dt_proj_b = (const float*)d_in[12];
    const float* A_log     = (const float*)d_in[13];
    const float* Dp        = (const float*)d_in[14];
    const float* out_proj_w= (const float*)d_in[15];
    const float* norm_w    = (const float*)d_in[16];
    const float* norm_b    = (const float*)d_in[17];
    const float* norm_acc_w= (const float*)d_in[18];
    const float* norm_acc_b= (const float*)d_in[19];
    const float* norm_ang_w= (const float*)d_in[20];
    const float* norm_ang_b= (const float*)d_in[21];
    const float* attn_in_w = (const float*)d_in[22];
    const float* attn_in_b = (const float*)d_in[23];
    const float* attn_out_w= (const float*)d_in[24];
    const float* attn_out_b= (const float*)d_in[25];

    float* ws = (float*)d_ws;
    // workspace layout (floats)
    float* accE = ws;                    //  2,097,152
    float* angE = ws + 2097152;          //  2,097,152
    float* xi   = ws + 4194304;          //  4,194,304 (dead after conv -> reused for hmid/dsums)
    float* zb   = ws + 8388608;          //  4,194,304
    float* xc   = ws + 12582912;         //  4,194,304
    float* dblb = ws + 16777216;         //    393,216
    float* dltb = ws + 17170432;         //  4,194,304
    float* yg   = ws + 21364736;         //  4,194,304
    float* mo   = ws + 25559040;         //  2,097,152
    float* hcat = ws + 27656192;         //  6,291,456
    float* atto = ws + 33947648;         //  6,291,456
    float* qkvb = ws;                    // alias: 18,874,368 (mamba bufs dead by then)
    float* hmid = ws + 4194304;          // alias of xi: 2,097,152 floats
    float* dsums= ws + 6291456;          // alias of xi tail: 131,072 floats

    // 1. embeds
    embed_k<<<dim3(BB * LL), dim3(256), 0, stream>>>(
        accele, angle, acc_w, acc_b, ang_w, ang_b, accE, angE);

    // 2. in_proj: xz = accE @ in_proj_w.T  -> split xi | z
    gemm_nt<1><<<dim3(1024 / 64, (BB * LL) / 64), dim3(256), 0, stream>>>(
        accE, in_proj_w, nullptr, xi, zb, BB * LL, 1024, DM);

    // 3. causal depthwise conv + SiLU
    conv_silu_k<<<dim3((BB * LL * DI) / 256), dim3(256), 0, stream>>>(
        xi, conv_w, conv_b, xc);

    // 4. x_proj -> dbl (dt|B|C)
    xproj_k<<<dim3(BB * LL), dim3(64), 0, stream>>>(xc, x_proj_w, dblb);

    // 5. delta = softplus(dt @ dt_proj_w.T + dt_proj_b)
    delta_k<<<dim3((BB * LL * DI) / 256), dim3(256), 0, stream>>>(
        dblb, dt_proj_w, dt_proj_b, dltb);

    // 6. chunked selective scan + gate
    scan1_k<<<dim3(BB * CH), dim3(512), 0, stream>>>(
        dltb, xc, dblb, A_log, hmid, dsums);
    scan2_k<<<dim3(64), dim3(64), 0, stream>>>(A_log, hmid, dsums);
    scan3_k<<<dim3(BB * CH), dim3(512), 0, stream>>>(
        dltb, xc, dblb, zb, A_log, Dp, hmid, yg);

    // 7. out_proj -> mamba output
    gemm_nt<0><<<dim3(DM / 64, (BB * LL) / 64), dim3(256), 0, stream>>>(
        yg, out_proj_w, nullptr, mo, nullptr, BB * LL, DM, DI);

    // 8. 3x LayerNorm -> hcat (B, 3L, 256)
    ln_concat_k<<<dim3(BB * 3 * LL), dim3(64), 0, stream>>>(
        x, mo, angE, norm_w, norm_b, norm_acc_w, norm_acc_b,
        norm_ang_w, norm_ang_b, hcat);

    // 9. qkv = hcat @ attn_in_w.T + attn_in_b
    gemm_nt<2><<<dim3(768 / 64, (BB * 3 * LL) / 64), dim3(256), 0, stream>>>(
        hcat, attn_in_w, attn_in_b, qkvb, nullptr, BB * 3 * LL, 768, DM);

    // 10. attention over S=8
    attn_k<<<dim3(3 * LL), dim3(64), 0, stream>>>(qkvb, atto);

    // 11. out-proj + bias + scatter into (8,1024,768) output
    gemm_nt<3><<<dim3(DM / 64, (BB * 3 * LL) / 64), dim3(256), 0, stream>>>(
        atto, attn_out_w, attn_out_b, (float*)d_out, nullptr, BB * 3 * LL, DM, DM);
}

// Round 3
// 463.875 us; speedup vs baseline: 2.5689x; 1.3423x over previous
//
#include <hip/hip_runtime.h>

// Problem constants
#define BB 8
#define LL 1024
#define DM 256
#define NH 8
#define DI 512
#define DS 16
#define DC 4
#define DR 16

// chunked-scan constants
#define CH 32
#define CL 32

typedef short bf16x8 __attribute__((ext_vector_type(8)));
typedef float f32x4 __attribute__((ext_vector_type(4)));
typedef unsigned short u16;

// split fp32 -> bf16 hi + bf16 lo (x ~= hi + lo, ~16 mantissa bits total)
__device__ __forceinline__ void splitf(float x, u16& h, u16& l) {
    union { float f; unsigned u; } a; a.f = x;
    unsigned r = (a.u + 0x7fffu + ((a.u >> 16) & 1u)) & 0xffff0000u;
    h = (u16)(r >> 16);
    union { unsigned u; float f; } b; b.u = r;
    const float res = x - b.f;
    union { float f; unsigned u; } c; c.f = res;
    l = (u16)((c.u + 0x7fffu + ((c.u >> 16) & 1u)) >> 16);
}

// ---------------------------------------------------------------------------
// K1: embed -> accE (bf16 hi/lo for MFMA GEMM), angE fp32 (LN consumes it)
// ---------------------------------------------------------------------------
__global__ __launch_bounds__(256) void embed_k(
    const float* __restrict__ accele, const float* __restrict__ angle,
    const float* __restrict__ acc_w, const float* __restrict__ acc_b,
    const float* __restrict__ ang_w, const float* __restrict__ ang_b,
    u16* __restrict__ accE_hi, u16* __restrict__ accE_lo,
    float* __restrict__ angE)
{
    const int row = blockIdx.x;
    const int d = threadIdx.x;
    const float* a_in = accele + (size_t)row * 12;
    const float* g_in = angle + (size_t)row * 12;
    float sa = acc_b[d], sg = ang_b[d];
    #pragma unroll
    for (int j = 0; j < 12; ++j) {
        sa = fmaf(a_in[j], acc_w[d * 12 + j], sa);
        sg = fmaf(g_in[j], ang_w[d * 12 + j], sg);
    }
    u16 h, l; splitf(sa, h, l);
    accE_hi[(size_t)row * DM + d] = h;
    accE_lo[(size_t)row * DM + d] = l;
    angE[(size_t)row * DM + d] = sg;
}

// ---------------------------------------------------------------------------
// Weight converters (fp32 -> bf16 hi/lo), into dead workspace regions
// ---------------------------------------------------------------------------
__global__ __launch_bounds__(256) void wconv1_k(
    const float* __restrict__ w, u16* __restrict__ hi, u16* __restrict__ lo)
{
    const int i = blockIdx.x * 256 + threadIdx.x;   // 262144 = in_proj_w
    u16 h, l; splitf(w[i], h, l);
    hi[i] = h; lo[i] = l;
}

__global__ __launch_bounds__(256) void wconv2_k(
    const float* __restrict__ ow, const float* __restrict__ aiw,
    const float* __restrict__ aow, u16* __restrict__ base)
{
    const int i = blockIdx.x * 256 + threadIdx.x;   // 393216 total
    float v; u16 *hp, *lp; int off;
    if (i < 131072)      { off = i;          v = ow[off];  hp = base;          lp = base + 131072; }
    else if (i < 327680) { off = i - 131072; v = aiw[off]; hp = base + 262144; lp = base + 458752; }
    else                 { off = i - 327680; v = aow[off]; hp = base + 655360; lp = base + 720896; }
    u16 h, l; splitf(v, h, l);
    hp[off] = h; lp[off] = l;
}

// ---------------------------------------------------------------------------
// MFMA NT GEMM, bf16x3 split: C[m,n] = sum_k A[m,k]*W[n,k] (+ epilogue)
// 128x128 tile, BK=32, 4 waves (2x2 of 64x64), 16x16x32 bf16 MFMA.
// A,W given as separate hi/lo bf16 buffers (K-contiguous rows).
// LDS stride 40 elems (80 B) -> worst-case 2-way bank aliasing (free).
// EPI 0: C0[m*N+n]=v   EPI 1: split n<512 -> C0|C1   EPI 2: +bias
// EPI 3: +bias, scatter to out(8,1024,768)
// ---------------------------------------------------------------------------
template<int EPI>
__global__ __launch_bounds__(256) void gemm_mfma(
    const u16* __restrict__ Ahi, const u16* __restrict__ Alo,
    const u16* __restrict__ Whi, const u16* __restrict__ Wlo,
    const float* __restrict__ bias,
    float* __restrict__ C0, float* __restrict__ C1,
    int M, int N, int K)
{
    __shared__ __align__(16) u16 Ash[128 * 40];
    __shared__ __align__(16) u16 Asl[128 * 40];
    __shared__ __align__(16) u16 Bsh[128 * 40];
    __shared__ __align__(16) u16 Bsl[128 * 40];
    const int t = threadIdx.x;
    const int m0 = blockIdx.y << 7, n0 = blockIdx.x << 7;
    const int lane = t & 63, wave = t >> 6;
    const int wr = wave >> 1, wc = wave & 1;
    const int ln = lane & 15, quad = lane >> 4;

    f32x4 acc[4][4];
    #pragma unroll
    for (int i = 0; i < 4; ++i)
        #pragma unroll
        for (int j = 0; j < 4; ++j) acc[i][j] = (f32x4){0.f, 0.f, 0.f, 0.f};

    // staging: 512 chunks of 16B per buffer; thread t does chunks t, t+256
    const int r0 = t >> 2, sgo = (t & 3) << 3;      // row, col-seg (elems)
    const int r1 = r0 + 64;
    const size_t arow0 = (size_t)(m0 + r0) * K + sgo;
    const size_t arow1 = (size_t)(m0 + r1) * K + sgo;
    const size_t brow0 = (size_t)(n0 + r0) * K + sgo;
    const size_t brow1 = (size_t)(n0 + r1) * K + sgo;
    const int l0 = r0 * 40 + sgo, l1 = r1 * 40 + sgo;

    for (int k0 = 0; k0 < K; k0 += 32) {
        __syncthreads();
        *(uint4*)&Ash[l0] = *(const uint4*)(Ahi + arow0 + k0);
        *(uint4*)&Ash[l1] = *(const uint4*)(Ahi + arow1 + k0);
        *(uint4*)&Asl[l0] = *(const uint4*)(Alo + arow0 + k0);
        *(uint4*)&Asl[l1] = *(const uint4*)(Alo + arow1 + k0);
        *(uint4*)&Bsh[l0] = *(const uint4*)(Whi + brow0 + k0);
        *(uint4*)&Bsh[l1] = *(const uint4*)(Whi + brow1 + k0);
        *(uint4*)&Bsl[l0] = *(const uint4*)(Wlo + brow0 + k0);
        *(uint4*)&Bsl[l1] = *(const uint4*)(Wlo + brow1 + k0);
        __syncthreads();

        bf16x8 bh[4], bl[4], ah[4], al[4];
        #pragma unroll
        for (int j = 0; j < 4; ++j) {
            const int r = ((wc << 6) + (j << 4) + ln) * 40 + (quad << 3);
            bh[j] = *(const bf16x8*)&Bsh[r];
            bl[j] = *(const bf16x8*)&Bsl[r];
        }
        #pragma unroll
        for (int i = 0; i < 4; ++i) {
            const int r = ((wr << 6) + (i << 4) + ln) * 40 + (quad << 3);
            ah[i] = *(const bf16x8*)&Ash[r];
            al[i] = *(const bf16x8*)&Asl[r];
        }
        #pragma unroll
        for (int i = 0; i < 4; ++i)
            #pragma unroll
            for (int j = 0; j < 4; ++j) {
                acc[i][j] = __builtin_amdgcn_mfma_f32_16x16x32_bf16(al[i], bh[j], acc[i][j], 0, 0, 0);
                acc[i][j] = __builtin_amdgcn_mfma_f32_16x16x32_bf16(ah[i], bl[j], acc[i][j], 0, 0, 0);
                acc[i][j] = __builtin_amdgcn_mfma_f32_16x16x32_bf16(ah[i], bh[j], acc[i][j], 0, 0, 0);
            }
    }

    // epilogue: C/D layout col=lane&15, row=quad*4+reg
    #pragma unroll
    for (int j = 0; j < 4; ++j) {
        const int n = n0 + (wc << 6) + (j << 4) + ln;
        const float bv = (EPI >= 2) ? bias[n] : 0.f;
        #pragma unroll
        for (int i = 0; i < 4; ++i) {
            const int mb = m0 + (wr << 6) + (i << 4) + (quad << 2);
            #pragma unroll
            for (int r = 0; r < 4; ++r) {
                const int m = mb + r;
                float v = acc[i][j][r];
                if (EPI == 0) {
                    C0[(size_t)m * N + n] = v;
                } else if (EPI == 1) {
                    if (n < 512) C0[(size_t)m * 512 + n] = v;
                    else         C1[(size_t)m * 512 + (n - 512)] = v;
                } else if (EPI == 2) {
                    C0[(size_t)m * N + n] = v + bv;
                } else {
                    v += bv;
                    const int b = m / 3072;
                    const int pos = m - b * 3072;
                    const int seg = pos >> 10;
                    const int l = pos & 1023;
                    C0[(size_t)((b << 10) + l) * 768 + seg * 256 + n] = v;
                }
            }
        }
    }
}

// ---------------------------------------------------------------------------
// K3: depthwise causal conv(4) + bias + SiLU.
// ---------------------------------------------------------------------------
__global__ __launch_bounds__(256) void conv_silu_k(
    const float* __restrict__ xi, const float* __restrict__ cw,
    const float* __restrict__ cb, float* __restrict__ xc)
{
    const size_t idx = (size_t)blockIdx.x * 256 + threadIdx.x;
    const int d = (int)(idx & 511);
    const int l = (int)((idx >> 9) & 1023);
    const float4 w4 = ((const float4*)cw)[d];
    const float* p = xi + idx;
    float s = cb[d];
    s = fmaf((l >= 3 ? p[-3 * 512] : 0.f), w4.x, s);
    s = fmaf((l >= 2 ? p[-2 * 512] : 0.f), w4.y, s);
    s = fmaf((l >= 1 ? p[-1 * 512] : 0.f), w4.z, s);
    s = fmaf(p[0], w4.w, s);
    xc[idx] = s / (1.f + __expf(-s));
}

// ---------------------------------------------------------------------------
// K4: x_proj  dbl[row, j<48] = xc[row,:] . x_proj_w[j,:]   (K=512)
// ---------------------------------------------------------------------------
__global__ __launch_bounds__(64) void xproj_k(
    const float* __restrict__ xc, const float* __restrict__ w,
    float* __restrict__ dbl)
{
    __shared__ float4 rb[128];
    const int row = blockIdx.x;
    const float4* src = (const float4*)(xc + (size_t)row * DI);
    rb[threadIdx.x] = src[threadIdx.x];
    rb[threadIdx.x + 64] = src[threadIdx.x + 64];
    __syncthreads();
    const int j = threadIdx.x;
    if (j < 48) {
        const float4* wr = (const float4*)(w + (size_t)j * DI);
        float s = 0.f;
        #pragma unroll 8
        for (int k = 0; k < 128; ++k) {
            float4 a = rb[k]; float4 b = wr[k];
            s = fmaf(a.x, b.x, s); s = fmaf(a.y, b.y, s);
            s = fmaf(a.z, b.z, s); s = fmaf(a.w, b.w, s);
        }
        dbl[(size_t)row * 48 + j] = s;
    }
}

// ---------------------------------------------------------------------------
// K5: delta = softplus(dt @ dt_proj_w.T + dt_proj_b)
// ---------------------------------------------------------------------------
__global__ __launch_bounds__(256) void delta_k(
    const float* __restrict__ dbl, const float* __restrict__ dtw,
    const float* __restrict__ dtb, float* __restrict__ dlt)
{
    const size_t idx = (size_t)blockIdx.x * 256 + threadIdx.x;
    const int d = (int)(idx & 511);
    const size_t row = idx >> 9;
    const float4* dr = (const float4*)(dbl + row * 48);
    const float4* wr = (const float4*)(dtw + (size_t)d * 16);
    float s = dtb[d];
    #pragma unroll
    for (int r = 0; r < 4; ++r) {
        float4 a = dr[r]; float4 b = wr[r];
        s = fmaf(a.x, b.x, s); s = fmaf(a.y, b.y, s);
        s = fmaf(a.z, b.z, s); s = fmaf(a.w, b.w, s);
    }
    dlt[idx] = (s > 20.f) ? s : log1pf(__expf(s));
}

// ---------------------------------------------------------------------------
// Chunked selective scan (3 passes), scan3 fuses gate and writes yg hi/lo
// ---------------------------------------------------------------------------
__global__ __launch_bounds__(512) void scan1_k(
    const float* __restrict__ dlt, const float* __restrict__ xc,
    const float* __restrict__ dbl, const float* __restrict__ A_log,
    float* __restrict__ hmid, float* __restrict__ dsums)
{
    __shared__ float Bs[CL][16];
    const int b = blockIdx.x >> 5;
    const int c = blockIdx.x & 31;
    const int d = threadIdx.x;
    const size_t rowbase = (size_t)b * LL + (size_t)c * CL;
    {
        const int l = threadIdx.x >> 4, s = threadIdx.x & 15;
        Bs[l][s] = dbl[(rowbase + l) * 48 + 16 + s];
    }
    __syncthreads();
    float A[16];
    #pragma unroll
    for (int s = 0; s < 16; ++s) A[s] = -__expf(A_log[(size_t)d * 16 + s]);
    float h[16];
    #pragma unroll
    for (int s = 0; s < 16; ++s) h[s] = 0.f;
    float dsum = 0.f;
    #pragma unroll 4
    for (int l = 0; l < CL; ++l) {
        const size_t row = rowbase + l;
        const float dv = dlt[row * DI + d];
        const float uv = xc[row * DI + d];
        const float du = dv * uv;
        dsum += dv;
        #pragma unroll
        for (int s = 0; s < 16; ++s)
            h[s] = fmaf(h[s], __expf(dv * A[s]), du * Bs[l][s]);
    }
    const size_t base = (size_t)(b * CH + c) * 16 * DI + d;
    #pragma unroll
    for (int s = 0; s < 16; ++s) hmid[base + (size_t)s * DI] = h[s];
    dsums[(size_t)(b * CH + c) * DI + d] = dsum;
}

__global__ __launch_bounds__(64) void scan2_k(
    const float* __restrict__ A_log, float* __restrict__ hmid,
    const float* __restrict__ dsums)
{
    const int b = blockIdx.x >> 3;
    const int d = ((blockIdx.x & 7) << 6) + threadIdx.x;
    float A[16];
    #pragma unroll
    for (int s = 0; s < 16; ++s) A[s] = -__expf(A_log[(size_t)d * 16 + s]);
    float h[16];
    #pragma unroll
    for (int s = 0; s < 16; ++s) h[s] = 0.f;

    size_t base = (size_t)(b * CH) * 16 * DI + d;
    float tmp[16];
    #pragma unroll
    for (int s = 0; s < 16; ++s) tmp[s] = hmid[base + (size_t)s * DI];
    float ds = dsums[(size_t)(b * CH) * DI + d];

    for (int c = 0; c < CH; ++c) {
        const int cn = (c + 1 < CH) ? c + 1 : c;
        const size_t nbase = (size_t)(b * CH + cn) * 16 * DI + d;
        float ntmp[16];
        #pragma unroll
        for (int s = 0; s < 16; ++s) ntmp[s] = hmid[nbase + (size_t)s * DI];
        const float nds = dsums[(size_t)(b * CH + cn) * DI + d];
        #pragma unroll
        for (int s = 0; s < 16; ++s) {
            const float hin = h[s];
            hmid[base + (size_t)s * DI] = hin;
            h[s] = fmaf(hin, __expf(A[s] * ds), tmp[s]);
        }
        base = nbase; ds = nds;
        #pragma unroll
        for (int s = 0; s < 16; ++s) tmp[s] = ntmp[s];
    }
}

__global__ __launch_bounds__(512) void scan3_k(
    const float* __restrict__ dlt, const float* __restrict__ xc,
    const float* __restrict__ dbl, const float* __restrict__ zb,
    const float* __restrict__ A_log, const float* __restrict__ Dpp,
    const float* __restrict__ hmid,
    u16* __restrict__ yg_hi, u16* __restrict__ yg_lo)
{
    __shared__ float Bs[CL][16];
    __shared__ float Cs[CL][16];
    const int b = blockIdx.x >> 5;
    const int c = blockIdx.x & 31;
    const int d = threadIdx.x;
    const size_t rowbase = (size_t)b * LL + (size_t)c * CL;
    {
        const int l = threadIdx.x >> 4, s = threadIdx.x & 15;
        Bs[l][s] = dbl[(rowbase + l) * 48 + 16 + s];
        Cs[l][s] = dbl[(rowbase + l) * 48 + 32 + s];
    }
    __syncthreads();
    float A[16];
    #pragma unroll
    for (int s = 0; s < 16; ++s) A[s] = -__expf(A_log[(size_t)d * 16 + s]);
    float h[16];
    const size_t base = (size_t)(b * CH + c) * 16 * DI + d;
    #pragma unroll
    for (int s = 0; s < 16; ++s) h[s] = hmid[base + (size_t)s * DI];
    const float Dpv = Dpp[d];

    #pragma unroll 4
    for (int l = 0; l < CL; ++l) {
        const size_t row = rowbase + l;
        const float dv = dlt[row * DI + d];
        const float uv = xc[row * DI + d];
        const float zv = zb[row * DI + d];
        const float du = dv * uv;
        float y = 0.f;
        #pragma unroll
        for (int s = 0; s < 16; ++s) {
            h[s] = fmaf(h[s], __expf(dv * A[s]), du * Bs[l][s]);
            y = fmaf(h[s], Cs[l][s], y);
        }
        const float sig = 1.f / (1.f + __expf(-zv));
        const float out = (y + uv * Dpv) * (zv * sig);
        u16 hh, ll; splitf(out, hh, ll);
        yg_hi[row * DI + d] = hh;
        yg_lo[row * DI + d] = ll;
    }
}

// ---------------------------------------------------------------------------
// K8: 3x LayerNorm -> hcat (B,3L,256) as bf16 hi/lo
// ---------------------------------------------------------------------------
__global__ __launch_bounds__(64) void ln_concat_k(
    const float* __restrict__ x, const float* __restrict__ mo,
    const float* __restrict__ angE,
    const float* __restrict__ nw, const float* __restrict__ nb,
    const float* __restrict__ naw, const float* __restrict__ nab,
    const float* __restrict__ ngw, const float* __restrict__ ngb,
    u16* __restrict__ hcat_hi, u16* __restrict__ hcat_lo)
{
    const int rowo = blockIdx.x;
    const int b = rowo / 3072;
    const int pos = rowo - b * 3072;
    const int seg = pos >> 10;
    const int l = pos & 1023;
    const size_t srow = (size_t)b * LL + l;
    const float* src; const float* w; const float* bias;
    if (seg == 0)      { src = x    + srow * DM; w = nw;  bias = nb;  }
    else if (seg == 1) { src = mo   + srow * DM; w = naw; bias = nab; }
    else               { src = angE + srow * DM; w = ngw; bias = ngb; }

    const int lane = threadIdx.x;
    float4 v = *(const float4*)(src + lane * 4);
    float s  = v.x + v.y + v.z + v.w;
    float s2 = v.x * v.x + v.y * v.y + v.z * v.z + v.w * v.w;
    #pragma unroll
    for (int off = 32; off > 0; off >>= 1) {
        s  += __shfl_down(s, off);
        s2 += __shfl_down(s2, off);
    }
    s = __shfl(s, 0); s2 = __shfl(s2, 0);
    const float mean = s * (1.f / DM);
    const float var = s2 * (1.f / DM) - mean * mean;
    const float inv = rsqrtf(var + 1e-5f);
    float4 wv = *(const float4*)(w + lane * 4);
    float4 bv = *(const float4*)(bias + lane * 4);
    float o0 = (v.x - mean) * inv * wv.x + bv.x;
    float o1 = (v.y - mean) * inv * wv.y + bv.y;
    float o2 = (v.z - mean) * inv * wv.z + bv.z;
    float o3 = (v.w - mean) * inv * wv.w + bv.w;
    ushort4 hv, lv;
    splitf(o0, hv.x, lv.x); splitf(o1, hv.y, lv.y);
    splitf(o2, hv.z, lv.z); splitf(o3, hv.w, lv.w);
    *(ushort4*)(hcat_hi + (size_t)rowo * DM + lane * 4) = hv;
    *(ushort4*)(hcat_lo + (size_t)rowo * DM + lane * 4) = lv;
}

// ---------------------------------------------------------------------------
// K10: attention over S=8; writes atto as bf16 hi/lo
// ---------------------------------------------------------------------------
__global__ __launch_bounds__(64) void attn_k(
    const float* __restrict__ qkv,
    u16* __restrict__ atto_hi, u16* __restrict__ atto_lo)
{
    const int n = blockIdx.x;
    const int hd = threadIdx.x >> 3;
    const int s = threadIdx.x & 7;
    const float scale = 0.17677669529663687f;

    float q[32];
    {
        const float4* qp = (const float4*)(qkv + ((size_t)(s * 3072 + n)) * 768 + hd * 32);
        #pragma unroll
        for (int i = 0; i < 8; ++i) {
            float4 t = qp[i];
            q[i * 4 + 0] = t.x; q[i * 4 + 1] = t.y; q[i * 4 + 2] = t.z; q[i * 4 + 3] = t.w;
        }
    }
    float sc[8];
    #pragma unroll
    for (int t = 0; t < 8; ++t) {
        const float4* kp = (const float4*)(qkv + ((size_t)(t * 3072 + n)) * 768 + 256 + hd * 32);
        float dot = 0.f;
        #pragma unroll
        for (int i = 0; i < 8; ++i) {
            float4 kv = kp[i];
            dot = fmaf(q[i * 4 + 0], kv.x, dot);
            dot = fmaf(q[i * 4 + 1], kv.y, dot);
            dot = fmaf(q[i * 4 + 2], kv.z, dot);
            dot = fmaf(q[i * 4 + 3], kv.w, dot);
        }
        sc[t] = dot * scale;
    }
    float mx = sc[0];
    #pragma unroll
    for (int t = 1; t < 8; ++t) mx = fmaxf(mx, sc[t]);
    float se = 0.f;
    #pragma unroll
    for (int t = 0; t < 8; ++t) { sc[t] = __expf(sc[t] - mx); se += sc[t]; }
    const float inv = 1.f / se;

    float o[32];
    #pragma unroll
    for (int i = 0; i < 32; ++i) o[i] = 0.f;
    #pragma unroll
    for (int t = 0; t < 8; ++t) {
        const float4* vp = (const float4*)(qkv + ((size_t)(t * 3072 + n)) * 768 + 512 + hd * 32);
        const float wgt = sc[t] * inv;
        #pragma unroll
        for (int i = 0; i < 8; ++i) {
            float4 vv = vp[i];
            o[i * 4 + 0] = fmaf(wgt, vv.x, o[i * 4 + 0]);
            o[i * 4 + 1] = fmaf(wgt, vv.y, o[i * 4 + 1]);
            o[i * 4 + 2] = fmaf(wgt, vv.z, o[i * 4 + 2]);
            o[i * 4 + 3] = fmaf(wgt, vv.w, o[i * 4 + 3]);
        }
    }
    const size_t base = ((size_t)(s * 3072 + n)) * 256 + hd * 32;
    #pragma unroll
    for (int g = 0; g < 8; ++g) {
        ushort4 hv, lv;
        splitf(o[g * 4 + 0], hv.x, lv.x);
        splitf(o[g * 4 + 1], hv.y, lv.y);
        splitf(o[g * 4 + 2], hv.z, lv.z);
        splitf(o[g * 4 + 3], hv.w, lv.w);
        *(ushort4*)(atto_hi + base + g * 4) = hv;
        *(ushort4*)(atto_lo + base + g * 4) = lv;
    }
}

// ---------------------------------------------------------------------------
extern "C" void kernel_launch(void* const* d_in, const int* in_sizes, int n_in,
                              void* d_out, int out_size, void* d_ws, size_t ws_size,
                              hipStream_t stream) {
    const float* x         = (const float*)d_in[0];
    const float* accele    = (const float*)d_in[1];
    const float* angle     = (const float*)d_in[2];
    const float* acc_w     = (const float*)d_in[3];
    const float* acc_b     = (const float*)d_in[4];
    const float* ang_w     = (const float*)d_in[5];
    const float* ang_b     = (const float*)d_in[6];
    const float* in_proj_w = (const float*)d_in[7];
    const float* conv_w    = (const float*)d_in[8];
    const float* conv_b    = (const float*)d_in[9];
    const float* x_proj_w  = (const float*)d_in[10];
    const float* dt_proj_w = (const float*)d_in[11];
    const float* dt_proj_b = (const float*)d_in[12];
    const float* A_log     = (const float*)d_in[13];
    const float* Dp        = (const float*)d_in[14];
    const float* out_proj_w= (const float*)d_in[15];
    const float* norm_w    = (const float*)d_in[16];
    const float* norm_b    = (const float*)d_in[17];
    const float* norm_acc_w= (const float*)d_in[18];
    const float* norm_acc_b= (const float*)d_in[19];
    const float* norm_ang_w= (const float*)d_in[20];
    const float* norm_ang_b= (const float*)d_in[21];
    const float* attn_in_w = (const float*)d_in[22];
    const float* attn_in_b = (const float*)d_in[23];
    const float* attn_out_w= (const float*)d_in[24];
    const float* attn_out_b= (const float*)d_in[25];

    float* ws = (float*)d_ws;
    // workspace layout (float units); total 40,239,104 floats (unchanged)
    u16*   accE_hi = (u16*)(ws);                   // [0, 1M)
    u16*   accE_lo = (u16*)(ws + 1048576);         // [1M, 2M)
    float* angE    = ws + 2097152;                 // [2M, 4M)
    float* xi      = ws + 4194304;                 // [4M, 8M)   dead after conv
    float* zb      = ws + 8388608;                 // [8M, 12M)
    float* xc      = ws + 12582912;                // [12M, 16M)
    float* dblb    = ws + 16777216;                // [16.78M, 17.17M)
    float* dltb    = ws + 17170432;                // [17.17M, 21.36M)
    u16*   wcv     = (u16*)(ws + 18874368);        // weight hi/lo region (inside dltb,
                                                   //  timeline-safe; see launch order)
    float* hmid    = ws + 4194304;                 // alias xi
    float* dsums   = ws + 6291456;                 // alias xi tail
    u16*   yg_hi   = (u16*)(ws + 21364736);        // [21.36M, 23.46M)
    u16*   yg_lo   = (u16*)(ws + 23461888);        // [23.46M, 25.56M)
    float* mo      = ws + 25559040;                // [25.56M, 27.66M)
    u16*   hcat_hi = (u16*)(ws + 27656192);        // [27.66M, 30.80M)
    u16*   hcat_lo = (u16*)(ws + 30801920);        // [30.80M, 33.95M)
    u16*   atto_hi = (u16*)(ws + 33947648);        // [33.95M, 37.09M)
    u16*   atto_lo = (u16*)(ws + 37093376);        // [37.09M, 40.24M)
    float* qkvb    = ws;                           // alias [0, 18.87M): mamba bufs dead

    // weight hi/lo sub-pointers
    u16* inw_hi = wcv;            u16* inw_lo = wcv + 262144;   // wconv1 (clobbered by delta_k, after use)
    u16* ow_hi  = wcv;            u16* ow_lo  = wcv + 131072;   // wconv2 (after scan3)
    u16* aiw_hi = wcv + 262144;   u16* aiw_lo = wcv + 458752;
    u16* aow_hi = wcv + 655360;   u16* aow_lo = wcv + 720896;

    // 0. in_proj weight split (region unused until delta_k writes dltb)
    wconv1_k<<<dim3(1024), dim3(256), 0, stream>>>(in_proj_w, inw_hi, inw_lo);

    // 1. embeds
    embed_k<<<dim3(BB * LL), dim3(256), 0, stream>>>(
        accele, angle, acc_w, acc_b, ang_w, ang_b, accE_hi, accE_lo, angE);

    // 2. in_proj (MFMA): xz = accE @ in_proj_w.T -> split xi | z
    gemm_mfma<1><<<dim3(1024 / 128, (BB * LL) / 128), dim3(256), 0, stream>>>(
        accE_hi, accE_lo, inw_hi, inw_lo, nullptr, xi, zb, BB * LL, 1024, DM);

    // 3. causal depthwise conv + SiLU
    conv_silu_k<<<dim3((BB * LL * DI) / 256), dim3(256), 0, stream>>>(
        xi, conv_w, conv_b, xc);

    // 4. x_proj -> dbl (dt|B|C)
    xproj_k<<<dim3(BB * LL), dim3(64), 0, stream>>>(xc, x_proj_w, dblb);

    // 5. delta (writes dltb; in_proj weights now dead)
    delta_k<<<dim3((BB * LL * DI) / 256), dim3(256), 0, stream>>>(
        dblb, dt_proj_w, dt_proj_b, dltb);

    // 6. chunked selective scan + gate -> yg hi/lo
    scan1_k<<<dim3(BB * CH), dim3(512), 0, stream>>>(
        dltb, xc, dblb, A_log, hmid, dsums);
    scan2_k<<<dim3(64), dim3(64), 0, stream>>>(A_log, hmid, dsums);
    scan3_k<<<dim3(BB * CH), dim3(512), 0, stream>>>(
        dltb, xc, dblb, zb, A_log, Dp, hmid, yg_hi, yg_lo);

    // 6.5 remaining weight splits (dltb dead now; region untouched by qkvb)
    wconv2_k<<<dim3(1536), dim3(256), 0, stream>>>(
        out_proj_w, attn_in_w, attn_out_w, wcv);

    // 7. out_proj (MFMA) -> mo
    gemm_mfma<0><<<dim3(DM / 128, (BB * LL) / 128), dim3(256), 0, stream>>>(
        yg_hi, yg_lo, ow_hi, ow_lo, nullptr, mo, nullptr, BB * LL, DM, DI);

    // 8. 3x LayerNorm -> hcat hi/lo
    ln_concat_k<<<dim3(BB * 3 * LL), dim3(64), 0, stream>>>(
        x, mo, angE, norm_w, norm_b, norm_acc_w, norm_acc_b,
        norm_ang_w, norm_ang_b, hcat_hi, hcat_lo);

    // 9. qkv (MFMA, +bias) -> qkvb fp32
    gemm_mfma<2><<<dim3(768 / 128, (BB * 3 * LL) / 128), dim3(256), 0, stream>>>(
        hcat_hi, hcat_lo, aiw_hi, aiw_lo, attn_in_b, qkvb, nullptr,
        BB * 3 * LL, 768, DM);

    // 10. attention over S=8 -> atto hi/lo
    attn_k<<<dim3(3 * LL), dim3(64), 0, stream>>>(qkvb, atto_hi, atto_lo);

    // 11. attn out-proj (MFMA, +bias, scatter) -> d_out
    gemm_mfma<3><<<dim3(DM / 128, (BB * 3 * LL) / 128), dim3(256), 0, stream>>>(
        atto_hi, atto_lo, aow_hi, aow_lo, attn_out_b, (float*)d_out, nullptr,
        BB * 3 * LL, DM, DM);
}

// Round 4
// 402.539 us; speedup vs baseline: 2.9603x; 1.1524x over previous
//
#include <hip/hip_runtime.h>

// Problem constants
#define BB 8
#define LL 1024
#define DM 256
#define NH 8
#define DI 512
#define DS 16
#define DC 4
#define DR 16

// chunked-scan constants
#define CH 32
#define CL 32

typedef short bf16x8 __attribute__((ext_vector_type(8)));
typedef float f32x4 __attribute__((ext_vector_type(4)));
typedef unsigned short u16;

// split fp32 -> bf16 hi + bf16 lo (x ~= hi + lo, ~16 mantissa bits total)
__device__ __forceinline__ void splitf(float x, u16& h, u16& l) {
    union { float f; unsigned u; } a; a.f = x;
    unsigned r = (a.u + 0x7fffu + ((a.u >> 16) & 1u)) & 0xffff0000u;
    h = (u16)(r >> 16);
    union { unsigned u; float f; } b; b.u = r;
    const float res = x - b.f;
    union { float f; unsigned u; } c; c.f = res;
    l = (u16)((c.u + 0x7fffu + ((c.u >> 16) & 1u)) >> 16);
}

// ---------------------------------------------------------------------------
// K1: embed -> accE (bf16 hi/lo for MFMA GEMM), angE fp32 (LN consumes it)
// ---------------------------------------------------------------------------
__global__ __launch_bounds__(256) void embed_k(
    const float* __restrict__ accele, const float* __restrict__ angle,
    const float* __restrict__ acc_w, const float* __restrict__ acc_b,
    const float* __restrict__ ang_w, const float* __restrict__ ang_b,
    u16* __restrict__ accE_hi, u16* __restrict__ accE_lo,
    float* __restrict__ angE)
{
    const int row = blockIdx.x;
    const int d = threadIdx.x;
    const float* a_in = accele + (size_t)row * 12;
    const float* g_in = angle + (size_t)row * 12;
    float sa = acc_b[d], sg = ang_b[d];
    #pragma unroll
    for (int j = 0; j < 12; ++j) {
        sa = fmaf(a_in[j], acc_w[d * 12 + j], sa);
        sg = fmaf(g_in[j], ang_w[d * 12 + j], sg);
    }
    u16 h, l; splitf(sa, h, l);
    accE_hi[(size_t)row * DM + d] = h;
    accE_lo[(size_t)row * DM + d] = l;
    angE[(size_t)row * DM + d] = sg;
}

// ---------------------------------------------------------------------------
// Weight converters (fp32 -> bf16 hi/lo), into dead workspace regions
// ---------------------------------------------------------------------------
__global__ __launch_bounds__(256) void wconv1_k(
    const float* __restrict__ w, u16* __restrict__ hi, u16* __restrict__ lo)
{
    const int i = blockIdx.x * 256 + threadIdx.x;   // 262144 = in_proj_w
    u16 h, l; splitf(w[i], h, l);
    hi[i] = h; lo[i] = l;
}

__global__ __launch_bounds__(256) void wconv2_k(
    const float* __restrict__ ow, const float* __restrict__ aiw,
    const float* __restrict__ aow, u16* __restrict__ base)
{
    const int i = blockIdx.x * 256 + threadIdx.x;   // 393216 total
    float v; u16 *hp, *lp; int off;
    if (i < 131072)      { off = i;          v = ow[off];  hp = base;          lp = base + 131072; }
    else if (i < 327680) { off = i - 131072; v = aiw[off]; hp = base + 262144; lp = base + 458752; }
    else                 { off = i - 327680; v = aow[off]; hp = base + 655360; lp = base + 720896; }
    u16 h, l; splitf(v, h, l);
    hp[off] = h; lp[off] = l;
}

// pad x_proj_w (48x512) -> wpad (64x512, zero rows 48..63)
__global__ __launch_bounds__(256) void wpad_k(
    const float* __restrict__ w, float* __restrict__ wpad)
{
    const int i = blockIdx.x * 256 + threadIdx.x;   // < 32768
    const int row = i >> 9;
    wpad[i] = (row < 48) ? w[i] : 0.f;
}

// ---------------------------------------------------------------------------
// MFMA NT GEMM, bf16x3 split: C[m,n] = sum_k A[m,k]*W[n,k] (+ epilogue)
// 128x128 tile, BK=32, 4 waves (2x2 of 64x64), 16x16x32 bf16 MFMA.
// ---------------------------------------------------------------------------
template<int EPI>
__global__ __launch_bounds__(256) void gemm_mfma(
    const u16* __restrict__ Ahi, const u16* __restrict__ Alo,
    const u16* __restrict__ Whi, const u16* __restrict__ Wlo,
    const float* __restrict__ bias,
    float* __restrict__ C0, float* __restrict__ C1,
    int M, int N, int K)
{
    __shared__ __align__(16) u16 Ash[128 * 40];
    __shared__ __align__(16) u16 Asl[128 * 40];
    __shared__ __align__(16) u16 Bsh[128 * 40];
    __shared__ __align__(16) u16 Bsl[128 * 40];
    const int t = threadIdx.x;
    const int m0 = blockIdx.y << 7, n0 = blockIdx.x << 7;
    const int lane = t & 63, wave = t >> 6;
    const int wr = wave >> 1, wc = wave & 1;
    const int ln = lane & 15, quad = lane >> 4;

    f32x4 acc[4][4];
    #pragma unroll
    for (int i = 0; i < 4; ++i)
        #pragma unroll
        for (int j = 0; j < 4; ++j) acc[i][j] = (f32x4){0.f, 0.f, 0.f, 0.f};

    const int r0 = t >> 2, sgo = (t & 3) << 3;
    const int r1 = r0 + 64;
    const size_t arow0 = (size_t)(m0 + r0) * K + sgo;
    const size_t arow1 = (size_t)(m0 + r1) * K + sgo;
    const size_t brow0 = (size_t)(n0 + r0) * K + sgo;
    const size_t brow1 = (size_t)(n0 + r1) * K + sgo;
    const int l0 = r0 * 40 + sgo, l1 = r1 * 40 + sgo;

    for (int k0 = 0; k0 < K; k0 += 32) {
        __syncthreads();
        *(uint4*)&Ash[l0] = *(const uint4*)(Ahi + arow0 + k0);
        *(uint4*)&Ash[l1] = *(const uint4*)(Ahi + arow1 + k0);
        *(uint4*)&Asl[l0] = *(const uint4*)(Alo + arow0 + k0);
        *(uint4*)&Asl[l1] = *(const uint4*)(Alo + arow1 + k0);
        *(uint4*)&Bsh[l0] = *(const uint4*)(Whi + brow0 + k0);
        *(uint4*)&Bsh[l1] = *(const uint4*)(Whi + brow1 + k0);
        *(uint4*)&Bsl[l0] = *(const uint4*)(Wlo + brow0 + k0);
        *(uint4*)&Bsl[l1] = *(const uint4*)(Wlo + brow1 + k0);
        __syncthreads();

        bf16x8 bh[4], bl[4], ah[4], al[4];
        #pragma unroll
        for (int j = 0; j < 4; ++j) {
            const int r = ((wc << 6) + (j << 4) + ln) * 40 + (quad << 3);
            bh[j] = *(const bf16x8*)&Bsh[r];
            bl[j] = *(const bf16x8*)&Bsl[r];
        }
        #pragma unroll
        for (int i = 0; i < 4; ++i) {
            const int r = ((wr << 6) + (i << 4) + ln) * 40 + (quad << 3);
            ah[i] = *(const bf16x8*)&Ash[r];
            al[i] = *(const bf16x8*)&Asl[r];
        }
        #pragma unroll
        for (int i = 0; i < 4; ++i)
            #pragma unroll
            for (int j = 0; j < 4; ++j) {
                acc[i][j] = __builtin_amdgcn_mfma_f32_16x16x32_bf16(al[i], bh[j], acc[i][j], 0, 0, 0);
                acc[i][j] = __builtin_amdgcn_mfma_f32_16x16x32_bf16(ah[i], bl[j], acc[i][j], 0, 0, 0);
                acc[i][j] = __builtin_amdgcn_mfma_f32_16x16x32_bf16(ah[i], bh[j], acc[i][j], 0, 0, 0);
            }
    }

    #pragma unroll
    for (int j = 0; j < 4; ++j) {
        const int n = n0 + (wc << 6) + (j << 4) + ln;
        const float bv = (EPI >= 2) ? bias[n] : 0.f;
        #pragma unroll
        for (int i = 0; i < 4; ++i) {
            const int mb = m0 + (wr << 6) + (i << 4) + (quad << 2);
            #pragma unroll
            for (int r = 0; r < 4; ++r) {
                const int m = mb + r;
                float v = acc[i][j][r];
                if (EPI == 0) {
                    C0[(size_t)m * N + n] = v;
                } else if (EPI == 1) {
                    if (n < 512) C0[(size_t)m * 512 + n] = v;
                    else         C1[(size_t)m * 512 + (n - 512)] = v;
                } else if (EPI == 2) {
                    C0[(size_t)m * N + n] = v + bv;
                } else {
                    v += bv;
                    const int b = m / 3072;
                    const int pos = m - b * 3072;
                    const int seg = pos >> 10;
                    const int l = pos & 1023;
                    C0[(size_t)((b << 10) + l) * 768 + seg * 256 + n] = v;
                }
            }
        }
    }
}

// ---------------------------------------------------------------------------
// fp32 NT GEMM (round-2 vintage), used for the skinny x_proj (N=64, K=512)
// ---------------------------------------------------------------------------
__global__ __launch_bounds__(256) void gemm_nt0(
    const float* __restrict__ A, const float* __restrict__ W,
    float* __restrict__ C0, int M, int N, int K)
{
    __shared__ float As[16][64];
    __shared__ float Ws[16][64];
    const int tid = threadIdx.x;
    const int tx = tid & 15;
    const int ty = tid >> 4;
    const int m0 = blockIdx.y * 64;
    const int n0 = blockIdx.x * 64;
    const int lr = tid >> 2;
    const int lk = (tid & 3) << 2;
    const float* Ag = A + (size_t)(m0 + lr) * K + lk;
    const float* Wg = W + (size_t)(n0 + lr) * K + lk;
    float acc[4][4];
    #pragma unroll
    for (int i = 0; i < 4; ++i)
        #pragma unroll
        for (int j = 0; j < 4; ++j) acc[i][j] = 0.f;

    for (int k0 = 0; k0 < K; k0 += 16) {
        float4 a4 = *(const float4*)(Ag + k0);
        float4 w4 = *(const float4*)(Wg + k0);
        __syncthreads();
        As[lk + 0][lr] = a4.x; As[lk + 1][lr] = a4.y;
        As[lk + 2][lr] = a4.z; As[lk + 3][lr] = a4.w;
        Ws[lk + 0][lr] = w4.x; Ws[lk + 1][lr] = w4.y;
        Ws[lk + 2][lr] = w4.z; Ws[lk + 3][lr] = w4.w;
        __syncthreads();
        #pragma unroll
        for (int k = 0; k < 16; ++k) {
            float4 av = *(const float4*)&As[k][ty << 2];
            float4 wv = *(const float4*)&Ws[k][tx << 2];
            float a[4] = {av.x, av.y, av.z, av.w};
            float w[4] = {wv.x, wv.y, wv.z, wv.w};
            #pragma unroll
            for (int i = 0; i < 4; ++i)
                #pragma unroll
                for (int j = 0; j < 4; ++j)
                    acc[i][j] = fmaf(a[i], w[j], acc[i][j]);
        }
    }

    #pragma unroll
    for (int i = 0; i < 4; ++i) {
        const int m = m0 + (ty << 2) + i;
        #pragma unroll
        for (int j = 0; j < 4; ++j) {
            const int n = n0 + (tx << 2) + j;
            C0[(size_t)m * N + n] = acc[i][j];
        }
    }
}

// ---------------------------------------------------------------------------
// K3: depthwise causal conv(4) + bias + SiLU.
// ---------------------------------------------------------------------------
__global__ __launch_bounds__(256) void conv_silu_k(
    const float* __restrict__ xi, const float* __restrict__ cw,
    const float* __restrict__ cb, float* __restrict__ xc)
{
    const size_t idx = (size_t)blockIdx.x * 256 + threadIdx.x;
    const int d = (int)(idx & 511);
    const int l = (int)((idx >> 9) & 1023);
    const float4 w4 = ((const float4*)cw)[d];
    const float* p = xi + idx;
    float s = cb[d];
    s = fmaf((l >= 3 ? p[-3 * 512] : 0.f), w4.x, s);
    s = fmaf((l >= 2 ? p[-2 * 512] : 0.f), w4.y, s);
    s = fmaf((l >= 1 ? p[-1 * 512] : 0.f), w4.z, s);
    s = fmaf(p[0], w4.w, s);
    xc[idx] = s / (1.f + __expf(-s));
}

// ---------------------------------------------------------------------------
// K5: delta = softplus(dbl[:, :16] @ dt_proj_w.T + dt_proj_b)   (dbl stride 64)
// ---------------------------------------------------------------------------
__global__ __launch_bounds__(256) void delta_k(
    const float* __restrict__ dbl, const float* __restrict__ dtw,
    const float* __restrict__ dtb, float* __restrict__ dlt)
{
    const size_t idx = (size_t)blockIdx.x * 256 + threadIdx.x;
    const int d = (int)(idx & 511);
    const size_t row = idx >> 9;
    const float4* dr = (const float4*)(dbl + row * 64);
    const float4* wr = (const float4*)(dtw + (size_t)d * 16);
    float s = dtb[d];
    #pragma unroll
    for (int r = 0; r < 4; ++r) {
        float4 a = dr[r]; float4 b = wr[r];
        s = fmaf(a.x, b.x, s); s = fmaf(a.y, b.y, s);
        s = fmaf(a.z, b.z, s); s = fmaf(a.w, b.w, s);
    }
    dlt[idx] = (s > 20.f) ? s : log1pf(__expf(s));
}

// ---------------------------------------------------------------------------
// Chunked selective scan (3 passes), scan3 fuses gate and writes yg hi/lo
// dbl row stride is 64 (padded): B at +16, C at +32.
// ---------------------------------------------------------------------------
__global__ __launch_bounds__(512) void scan1_k(
    const float* __restrict__ dlt, const float* __restrict__ xc,
    const float* __restrict__ dbl, const float* __restrict__ A_log,
    float* __restrict__ hmid, float* __restrict__ dsums)
{
    __shared__ float Bs[CL][16];
    const int b = blockIdx.x >> 5;
    const int c = blockIdx.x & 31;
    const int d = threadIdx.x;
    const size_t rowbase = (size_t)b * LL + (size_t)c * CL;
    {
        const int l = threadIdx.x >> 4, s = threadIdx.x & 15;
        Bs[l][s] = dbl[(rowbase + l) * 64 + 16 + s];
    }
    __syncthreads();
    float A[16];
    #pragma unroll
    for (int s = 0; s < 16; ++s) A[s] = -__expf(A_log[(size_t)d * 16 + s]);
    float h[16];
    #pragma unroll
    for (int s = 0; s < 16; ++s) h[s] = 0.f;
    float dsum = 0.f;
    #pragma unroll 4
    for (int l = 0; l < CL; ++l) {
        const size_t row = rowbase + l;
        const float dv = dlt[row * DI + d];
        const float uv = xc[row * DI + d];
        const float du = dv * uv;
        dsum += dv;
        #pragma unroll
        for (int s = 0; s < 16; ++s)
            h[s] = fmaf(h[s], __expf(dv * A[s]), du * Bs[l][s]);
    }
    const size_t base = (size_t)(b * CH + c) * 16 * DI + d;
    #pragma unroll
    for (int s = 0; s < 16; ++s) hmid[base + (size_t)s * DI] = h[s];
    dsums[(size_t)(b * CH + c) * DI + d] = dsum;
}

__global__ __launch_bounds__(64) void scan2_k(
    const float* __restrict__ A_log, float* __restrict__ hmid,
    const float* __restrict__ dsums)
{
    const int b = blockIdx.x >> 3;
    const int d = ((blockIdx.x & 7) << 6) + threadIdx.x;
    float A[16];
    #pragma unroll
    for (int s = 0; s < 16; ++s) A[s] = -__expf(A_log[(size_t)d * 16 + s]);
    float h[16];
    #pragma unroll
    for (int s = 0; s < 16; ++s) h[s] = 0.f;

    size_t base = (size_t)(b * CH) * 16 * DI + d;
    float tmp[16];
    #pragma unroll
    for (int s = 0; s < 16; ++s) tmp[s] = hmid[base + (size_t)s * DI];
    float ds = dsums[(size_t)(b * CH) * DI + d];

    for (int c = 0; c < CH; ++c) {
        const int cn = (c + 1 < CH) ? c + 1 : c;
        const size_t nbase = (size_t)(b * CH + cn) * 16 * DI + d;
        float ntmp[16];
        #pragma unroll
        for (int s = 0; s < 16; ++s) ntmp[s] = hmid[nbase + (size_t)s * DI];
        const float nds = dsums[(size_t)(b * CH + cn) * DI + d];
        #pragma unroll
        for (int s = 0; s < 16; ++s) {
            const float hin = h[s];
            hmid[base + (size_t)s * DI] = hin;
            h[s] = fmaf(hin, __expf(A[s] * ds), tmp[s]);
        }
        base = nbase; ds = nds;
        #pragma unroll
        for (int s = 0; s < 16; ++s) tmp[s] = ntmp[s];
    }
}

__global__ __launch_bounds__(512) void scan3_k(
    const float* __restrict__ dlt, const float* __restrict__ xc,
    const float* __restrict__ dbl, const float* __restrict__ zb,
    const float* __restrict__ A_log, const float* __restrict__ Dpp,
    const float* __restrict__ hmid,
    u16* __restrict__ yg_hi, u16* __restrict__ yg_lo)
{
    __shared__ float Bs[CL][16];
    __shared__ float Cs[CL][16];
    const int b = blockIdx.x >> 5;
    const int c = blockIdx.x & 31;
    const int d = threadIdx.x;
    const size_t rowbase = (size_t)b * LL + (size_t)c * CL;
    {
        const int l = threadIdx.x >> 4, s = threadIdx.x & 15;
        Bs[l][s] = dbl[(rowbase + l) * 64 + 16 + s];
        Cs[l][s] = dbl[(rowbase + l) * 64 + 32 + s];
    }
    __syncthreads();
    float A[16];
    #pragma unroll
    for (int s = 0; s < 16; ++s) A[s] = -__expf(A_log[(size_t)d * 16 + s]);
    float h[16];
    const size_t base = (size_t)(b * CH + c) * 16 * DI + d;
    #pragma unroll
    for (int s = 0; s < 16; ++s) h[s] = hmid[base + (size_t)s * DI];
    const float Dpv = Dpp[d];

    #pragma unroll 4
    for (int l = 0; l < CL; ++l) {
        const size_t row = rowbase + l;
        const float dv = dlt[row * DI + d];
        const float uv = xc[row * DI + d];
        const float zv = zb[row * DI + d];
        const float du = dv * uv;
        float y = 0.f;
        #pragma unroll
        for (int s = 0; s < 16; ++s) {
            h[s] = fmaf(h[s], __expf(dv * A[s]), du * Bs[l][s]);
            y = fmaf(h[s], Cs[l][s], y);
        }
        const float sig = 1.f / (1.f + __expf(-zv));
        const float out = (y + uv * Dpv) * (zv * sig);
        u16 hh, ll; splitf(out, hh, ll);
        yg_hi[row * DI + d] = hh;
        yg_lo[row * DI + d] = ll;
    }
}

// ---------------------------------------------------------------------------
// K8: 3x LayerNorm -> hcat (B,3L,256) as bf16 hi/lo
// ---------------------------------------------------------------------------
__global__ __launch_bounds__(64) void ln_concat_k(
    const float* __restrict__ x, const float* __restrict__ mo,
    const float* __restrict__ angE,
    const float* __restrict__ nw, const float* __restrict__ nb,
    const float* __restrict__ naw, const float* __restrict__ nab,
    const float* __restrict__ ngw, const float* __restrict__ ngb,
    u16* __restrict__ hcat_hi, u16* __restrict__ hcat_lo)
{
    const int rowo = blockIdx.x;
    const int b = rowo / 3072;
    const int pos = rowo - b * 3072;
    const int seg = pos >> 10;
    const int l = pos & 1023;
    const size_t srow = (size_t)b * LL + l;
    const float* src; const float* w; const float* bias;
    if (seg == 0)      { src = x    + srow * DM; w = nw;  bias = nb;  }
    else if (seg == 1) { src = mo   + srow * DM; w = naw; bias = nab; }
    else               { src = angE + srow * DM; w = ngw; bias = ngb; }

    const int lane = threadIdx.x;
    float4 v = *(const float4*)(src + lane * 4);
    float s  = v.x + v.y + v.z + v.w;
    float s2 = v.x * v.x + v.y * v.y + v.z * v.z + v.w * v.w;
    #pragma unroll
    for (int off = 32; off > 0; off >>= 1) {
        s  += __shfl_down(s, off);
        s2 += __shfl_down(s2, off);
    }
    s = __shfl(s, 0); s2 = __shfl(s2, 0);
    const float mean = s * (1.f / DM);
    const float var = s2 * (1.f / DM) - mean * mean;
    const float inv = rsqrtf(var + 1e-5f);
    float4 wv = *(const float4*)(w + lane * 4);
    float4 bv = *(const float4*)(bias + lane * 4);
    float o0 = (v.x - mean) * inv * wv.x + bv.x;
    float o1 = (v.y - mean) * inv * wv.y + bv.y;
    float o2 = (v.z - mean) * inv * wv.z + bv.z;
    float o3 = (v.w - mean) * inv * wv.w + bv.w;
    ushort4 hv, lv;
    splitf(o0, hv.x, lv.x); splitf(o1, hv.y, lv.y);
    splitf(o2, hv.z, lv.z); splitf(o3, hv.w, lv.w);
    *(ushort4*)(hcat_hi + (size_t)rowo * DM + lane * 4) = hv;
    *(ushort4*)(hcat_lo + (size_t)rowo * DM + lane * 4) = lv;
}

// ---------------------------------------------------------------------------
// K10: attention over S=8; writes atto as bf16 hi/lo
// ---------------------------------------------------------------------------
__global__ __launch_bounds__(64) void attn_k(
    const float* __restrict__ qkv,
    u16* __restrict__ atto_hi, u16* __restrict__ atto_lo)
{
    const int n = blockIdx.x;
    const int hd = threadIdx.x >> 3;
    const int s = threadIdx.x & 7;
    const float scale = 0.17677669529663687f;

    float q[32];
    {
        const float4* qp = (const float4*)(qkv + ((size_t)(s * 3072 + n)) * 768 + hd * 32);
        #pragma unroll
        for (int i = 0; i < 8; ++i) {
            float4 t = qp[i];
            q[i * 4 + 0] = t.x; q[i * 4 + 1] = t.y; q[i * 4 + 2] = t.z; q[i * 4 + 3] = t.w;
        }
    }
    float sc[8];
    #pragma unroll
    for (int t = 0; t < 8; ++t) {
        const float4* kp = (const float4*)(qkv + ((size_t)(t * 3072 + n)) * 768 + 256 + hd * 32);
        float dot = 0.f;
        #pragma unroll
        for (int i = 0; i < 8; ++i) {
            float4 kv = kp[i];
            dot = fmaf(q[i * 4 + 0], kv.x, dot);
            dot = fmaf(q[i * 4 + 1], kv.y, dot);
            dot = fmaf(q[i * 4 + 2], kv.z, dot);
            dot = fmaf(q[i * 4 + 3], kv.w, dot);
        }
        sc[t] = dot * scale;
    }
    float mx = sc[0];
    #pragma unroll
    for (int t = 1; t < 8; ++t) mx = fmaxf(mx, sc[t]);
    float se = 0.f;
    #pragma unroll
    for (int t = 0; t < 8; ++t) { sc[t] = __expf(sc[t] - mx); se += sc[t]; }
    const float inv = 1.f / se;

    float o[32];
    #pragma unroll
    for (int i = 0; i < 32; ++i) o[i] = 0.f;
    #pragma unroll
    for (int t = 0; t < 8; ++t) {
        const float4* vp = (const float4*)(qkv + ((size_t)(t * 3072 + n)) * 768 + 512 + hd * 32);
        const float wgt = sc[t] * inv;
        #pragma unroll
        for (int i = 0; i < 8; ++i) {
            float4 vv = vp[i];
            o[i * 4 + 0] = fmaf(wgt, vv.x, o[i * 4 + 0]);
            o[i * 4 + 1] = fmaf(wgt, vv.y, o[i * 4 + 1]);
            o[i * 4 + 2] = fmaf(wgt, vv.z, o[i * 4 + 2]);
            o[i * 4 + 3] = fmaf(wgt, vv.w, o[i * 4 + 3]);
        }
    }
    const size_t base = ((size_t)(s * 3072 + n)) * 256 + hd * 32;
    #pragma unroll
    for (int g = 0; g < 8; ++g) {
        ushort4 hv, lv;
        splitf(o[g * 4 + 0], hv.x, lv.x);
        splitf(o[g * 4 + 1], hv.y, lv.y);
        splitf(o[g * 4 + 2], hv.z, lv.z);
        splitf(o[g * 4 + 3], hv.w, lv.w);
        *(ushort4*)(atto_hi + base + g * 4) = hv;
        *(ushort4*)(atto_lo + base + g * 4) = lv;
    }
}

// ---------------------------------------------------------------------------
extern "C" void kernel_launch(void* const* d_in, const int* in_sizes, int n_in,
                              void* d_out, int out_size, void* d_ws, size_t ws_size,
                              hipStream_t stream) {
    const float* x         = (const float*)d_in[0];
    const float* accele    = (const float*)d_in[1];
    const float* angle     = (const float*)d_in[2];
    const float* acc_w     = (const float*)d_in[3];
    const float* acc_b     = (const float*)d_in[4];
    const float* ang_w     = (const float*)d_in[5];
    const float* ang_b     = (const float*)d_in[6];
    const float* in_proj_w = (const float*)d_in[7];
    const float* conv_w    = (const float*)d_in[8];
    const float* conv_b    = (const float*)d_in[9];
    const float* x_proj_w  = (const float*)d_in[10];
    const float* dt_proj_w = (const float*)d_in[11];
    const float* dt_proj_b = (const float*)d_in[12];
    const float* A_log     = (const float*)d_in[13];
    const float* Dp        = (const float*)d_in[14];
    const float* out_proj_w= (const float*)d_in[15];
    const float* norm_w    = (const float*)d_in[16];
    const float* norm_b    = (const float*)d_in[17];
    const float* norm_acc_w= (const float*)d_in[18];
    const float* norm_acc_b= (const float*)d_in[19];
    const float* norm_ang_w= (const float*)d_in[20];
    const float* norm_ang_b= (const float*)d_in[21];
    const float* attn_in_w = (const float*)d_in[22];
    const float* attn_in_b = (const float*)d_in[23];
    const float* attn_out_w= (const float*)d_in[24];
    const float* attn_out_b= (const float*)d_in[25];

    float* ws = (float*)d_ws;
    // workspace layout (float units)
    u16*   accE_hi = (u16*)(ws);                   // [0, 1M)
    u16*   accE_lo = (u16*)(ws + 1048576);         // [1M, 2M)
    float* angE    = ws + 2097152;                 // [2M, 4M)
    float* xi      = ws + 4194304;                 // [4M, 8M)   dead after conv
    float* zb      = ws + 8388608;                 // [8M, 12M)
    float* xc      = ws + 12582912;                // [12M, 16M)
    float* dltb    = ws + 17170432;                // [17.17M, 21.36M)
    u16*   wcv     = (u16*)(ws + 18874368);        // weight hi/lo region (inside dltb)
    float* hmid    = ws + 4194304;                 // alias xi
    float* dsums   = ws + 6291456;                 // alias xi tail
    u16*   yg_hi   = (u16*)(ws + 21364736);        // [21.36M, 23.46M)
    u16*   yg_lo   = (u16*)(ws + 23461888);        // [23.46M, 25.56M)
    float* mo      = ws + 25559040;                // [25.56M, 27.66M) (written step 7)
    u16*   hcat_hi = (u16*)(ws + 27656192);        // [27.66M, 30.80M)
    u16*   hcat_lo = (u16*)(ws + 30801920);        // [30.80M, 33.95M)
    u16*   atto_hi = (u16*)(ws + 33947648);        // [33.95M, 37.09M)
    u16*   atto_lo = (u16*)(ws + 37093376);        // [37.09M, 40.24M)
    float* qkvb    = ws;                           // alias [0, 18.87M): mamba bufs dead
    // dblp (8192x64) + wpad (64x512) live in the mo region: mo is written only
    // at step 7, strictly after all dblp/wpad consumers (delta_k, scan1, scan3).
    float* dblp    = ws + 25559040;                // 524,288 floats
    float* wpad    = ws + 26083328;                // 131,072 floats (ends 26,214,400 < 27,656,192)

    // weight hi/lo sub-pointers
    u16* inw_hi = wcv;            u16* inw_lo = wcv + 262144;
    u16* ow_hi  = wcv;            u16* ow_lo  = wcv + 131072;
    u16* aiw_hi = wcv + 262144;   u16* aiw_lo = wcv + 458752;
    u16* aow_hi = wcv + 655360;   u16* aow_lo = wcv + 720896;

    // 0. weight prep
    wconv1_k<<<dim3(1024), dim3(256), 0, stream>>>(in_proj_w, inw_hi, inw_lo);
    wpad_k<<<dim3(128), dim3(256), 0, stream>>>(x_proj_w, wpad);

    // 1. embeds
    embed_k<<<dim3(BB * LL), dim3(256), 0, stream>>>(
        accele, angle, acc_w, acc_b, ang_w, ang_b, accE_hi, accE_lo, angE);

    // 2. in_proj (MFMA): xz = accE @ in_proj_w.T -> split xi | z
    gemm_mfma<1><<<dim3(1024 / 128, (BB * LL) / 128), dim3(256), 0, stream>>>(
        accE_hi, accE_lo, inw_hi, inw_lo, nullptr, xi, zb, BB * LL, 1024, DM);

    // 3. causal depthwise conv + SiLU
    conv_silu_k<<<dim3((BB * LL * DI) / 256), dim3(256), 0, stream>>>(
        xi, conv_w, conv_b, xc);

    // 4. x_proj as fp32 GEMM (N padded 48->64) -> dblp (dt|B|C|pad, stride 64)
    gemm_nt0<<<dim3(1, (BB * LL) / 64), dim3(256), 0, stream>>>(
        xc, wpad, dblp, BB * LL, 64, DI);

    // 5. delta (writes dltb; in_proj weights now dead)
    delta_k<<<dim3((BB * LL * DI) / 256), dim3(256), 0, stream>>>(
        dblp, dt_proj_w, dt_proj_b, dltb);

    // 6. chunked selective scan + gate -> yg hi/lo
    scan1_k<<<dim3(BB * CH), dim3(512), 0, stream>>>(
        dltb, xc, dblp, A_log, hmid, dsums);
    scan2_k<<<dim3(64), dim3(64), 0, stream>>>(A_log, hmid, dsums);
    scan3_k<<<dim3(BB * CH), dim3(512), 0, stream>>>(
        dltb, xc, dblp, zb, A_log, Dp, hmid, yg_hi, yg_lo);

    // 6.5 remaining weight splits (dltb region reuse is done; safe)
    wconv2_k<<<dim3(1536), dim3(256), 0, stream>>>(
        out_proj_w, attn_in_w, attn_out_w, wcv);

    // 7. out_proj (MFMA) -> mo (overwrites dblp/wpad — both dead now)
    gemm_mfma<0><<<dim3(DM / 128, (BB * LL) / 128), dim3(256), 0, stream>>>(
        yg_hi, yg_lo, ow_hi, ow_lo, nullptr, mo, nullptr, BB * LL, DM, DI);

    // 8. 3x LayerNorm -> hcat hi/lo
    ln_concat_k<<<dim3(BB * 3 * LL), dim3(64), 0, stream>>>(
        x, mo, angE, norm_w, norm_b, norm_acc_w, norm_acc_b,
        norm_ang_w, norm_ang_b, hcat_hi, hcat_lo);

    // 9. qkv (MFMA, +bias) -> qkvb fp32
    gemm_mfma<2><<<dim3(768 / 128, (BB * 3 * LL) / 128), dim3(256), 0, stream>>>(
        hcat_hi, hcat_lo, aiw_hi, aiw_lo, attn_in_b, qkvb, nullptr,
        BB * 3 * LL, 768, DM);

    // 10. attention over S=8 -> atto hi/lo
    attn_k<<<dim3(3 * LL), dim3(64), 0, stream>>>(qkvb, atto_hi, atto_lo);

    // 11. attn out-proj (MFMA, +bias, scatter) -> d_out
    gemm_mfma<3><<<dim3(DM / 128, (BB * 3 * LL) / 128), dim3(256), 0, stream>>>(
        atto_hi, atto_lo, aow_hi, aow_lo, attn_out_b, (float*)d_out, nullptr,
        BB * 3 * LL, DM, DM);
}

// Round 5
// 365.345 us; speedup vs baseline: 3.2617x; 1.1018x over previous
//
#include <hip/hip_runtime.h>

// Problem constants
#define BB 8
#define LL 1024
#define DM 256
#define NH 8
#define DI 512
#define DS 16
#define DC 4
#define DR 16

// chunked-scan constants
#define CH 32
#define CL 32

typedef short bf16x8 __attribute__((ext_vector_type(8)));
typedef float f32x4 __attribute__((ext_vector_type(4)));
typedef unsigned short u16;

// split fp32 -> bf16 hi + bf16 lo (x ~= hi + lo, ~16 mantissa bits total)
__device__ __forceinline__ void splitf(float x, u16& h, u16& l) {
    union { float f; unsigned u; } a; a.f = x;
    unsigned r = (a.u + 0x7fffu + ((a.u >> 16) & 1u)) & 0xffff0000u;
    h = (u16)(r >> 16);
    union { unsigned u; float f; } b; b.u = r;
    const float res = x - b.f;
    union { float f; unsigned u; } c; c.f = res;
    l = (u16)((c.u + 0x7fffu + ((c.u >> 16) & 1u)) >> 16);
}

// fp32 -> bf16 round-to-nearest-even
__device__ __forceinline__ u16 f2bf(float x) {
    union { float f; unsigned u; } a; a.f = x;
    return (u16)((a.u + 0x7fffu + ((a.u >> 16) & 1u)) >> 16);
}
// bf16 -> fp32
__device__ __forceinline__ float bf2f(u16 v) {
    union { unsigned u; float f; } a; a.u = ((unsigned)v) << 16;
    return a.f;
}

// ---------------------------------------------------------------------------
// K1: embed -> accE (bf16 hi/lo for MFMA GEMM), angE fp32 (LN consumes it)
// ---------------------------------------------------------------------------
__global__ __launch_bounds__(256) void embed_k(
    const float* __restrict__ accele, const float* __restrict__ angle,
    const float* __restrict__ acc_w, const float* __restrict__ acc_b,
    const float* __restrict__ ang_w, const float* __restrict__ ang_b,
    u16* __restrict__ accE_hi, u16* __restrict__ accE_lo,
    float* __restrict__ angE)
{
    const int row = blockIdx.x;
    const int d = threadIdx.x;
    const float* a_in = accele + (size_t)row * 12;
    const float* g_in = angle + (size_t)row * 12;
    float sa = acc_b[d], sg = ang_b[d];
    #pragma unroll
    for (int j = 0; j < 12; ++j) {
        sa = fmaf(a_in[j], acc_w[d * 12 + j], sa);
        sg = fmaf(g_in[j], ang_w[d * 12 + j], sg);
    }
    u16 h, l; splitf(sa, h, l);
    accE_hi[(size_t)row * DM + d] = h;
    accE_lo[(size_t)row * DM + d] = l;
    angE[(size_t)row * DM + d] = sg;
}

// ---------------------------------------------------------------------------
// Weight converters (fp32 -> bf16 hi/lo), into dead workspace regions
// ---------------------------------------------------------------------------
__global__ __launch_bounds__(256) void wconv1_k(
    const float* __restrict__ w, u16* __restrict__ hi, u16* __restrict__ lo)
{
    const int i = blockIdx.x * 256 + threadIdx.x;   // 262144 = in_proj_w
    u16 h, l; splitf(w[i], h, l);
    hi[i] = h; lo[i] = l;
}

__global__ __launch_bounds__(256) void wconv2_k(
    const float* __restrict__ ow, const float* __restrict__ aiw,
    const float* __restrict__ aow, u16* __restrict__ base)
{
    const int i = blockIdx.x * 256 + threadIdx.x;   // 393216 total
    float v; u16 *hp, *lp; int off;
    if (i < 131072)      { off = i;          v = ow[off];  hp = base;          lp = base + 131072; }
    else if (i < 327680) { off = i - 131072; v = aiw[off]; hp = base + 262144; lp = base + 458752; }
    else                 { off = i - 327680; v = aow[off]; hp = base + 655360; lp = base + 720896; }
    u16 h, l; splitf(v, h, l);
    hp[off] = h; lp[off] = l;
}

// pad x_proj_w (48x512) -> wpad (64x512, zero rows 48..63)
__global__ __launch_bounds__(256) void wpad_k(
    const float* __restrict__ w, float* __restrict__ wpad)
{
    const int i = blockIdx.x * 256 + threadIdx.x;   // < 32768
    const int row = i >> 9;
    wpad[i] = (row < 48) ? w[i] : 0.f;
}

// ---------------------------------------------------------------------------
// MFMA NT GEMM, bf16x3 split (A hi/lo, W hi/lo): high-precision path.
// 128x128 tile, BK=32, 4 waves (2x2 of 64x64), 16x16x32 bf16 MFMA.
// EPI 0: C0[m*N+n]=v   EPI 1: split n<512 -> C0 (xi) | C1 (z)
// ---------------------------------------------------------------------------
template<int EPI>
__global__ __launch_bounds__(256) void gemm_mfma(
    const u16* __restrict__ Ahi, const u16* __restrict__ Alo,
    const u16* __restrict__ Whi, const u16* __restrict__ Wlo,
    float* __restrict__ C0, float* __restrict__ C1,
    int M, int N, int K)
{
    __shared__ __align__(16) u16 Ash[128 * 40];
    __shared__ __align__(16) u16 Asl[128 * 40];
    __shared__ __align__(16) u16 Bsh[128 * 40];
    __shared__ __align__(16) u16 Bsl[128 * 40];
    const int t = threadIdx.x;
    const int m0 = blockIdx.y << 7, n0 = blockIdx.x << 7;
    const int lane = t & 63, wave = t >> 6;
    const int wr = wave >> 1, wc = wave & 1;
    const int ln = lane & 15, quad = lane >> 4;

    f32x4 acc[4][4];
    #pragma unroll
    for (int i = 0; i < 4; ++i)
        #pragma unroll
        for (int j = 0; j < 4; ++j) acc[i][j] = (f32x4){0.f, 0.f, 0.f, 0.f};

    const int r0 = t >> 2, sgo = (t & 3) << 3;
    const int r1 = r0 + 64;
    const size_t arow0 = (size_t)(m0 + r0) * K + sgo;
    const size_t arow1 = (size_t)(m0 + r1) * K + sgo;
    const size_t brow0 = (size_t)(n0 + r0) * K + sgo;
    const size_t brow1 = (size_t)(n0 + r1) * K + sgo;
    const int l0 = r0 * 40 + sgo, l1 = r1 * 40 + sgo;

    for (int k0 = 0; k0 < K; k0 += 32) {
        __syncthreads();
        *(uint4*)&Ash[l0] = *(const uint4*)(Ahi + arow0 + k0);
        *(uint4*)&Ash[l1] = *(const uint4*)(Ahi + arow1 + k0);
        *(uint4*)&Asl[l0] = *(const uint4*)(Alo + arow0 + k0);
        *(uint4*)&Asl[l1] = *(const uint4*)(Alo + arow1 + k0);
        *(uint4*)&Bsh[l0] = *(const uint4*)(Whi + brow0 + k0);
        *(uint4*)&Bsh[l1] = *(const uint4*)(Whi + brow1 + k0);
        *(uint4*)&Bsl[l0] = *(const uint4*)(Wlo + brow0 + k0);
        *(uint4*)&Bsl[l1] = *(const uint4*)(Wlo + brow1 + k0);
        __syncthreads();

        bf16x8 bh[4], bl[4], ah[4], al[4];
        #pragma unroll
        for (int j = 0; j < 4; ++j) {
            const int r = ((wc << 6) + (j << 4) + ln) * 40 + (quad << 3);
            bh[j] = *(const bf16x8*)&Bsh[r];
            bl[j] = *(const bf16x8*)&Bsl[r];
        }
        #pragma unroll
        for (int i = 0; i < 4; ++i) {
            const int r = ((wr << 6) + (i << 4) + ln) * 40 + (quad << 3);
            ah[i] = *(const bf16x8*)&Ash[r];
            al[i] = *(const bf16x8*)&Asl[r];
        }
        #pragma unroll
        for (int i = 0; i < 4; ++i)
            #pragma unroll
            for (int j = 0; j < 4; ++j) {
                acc[i][j] = __builtin_amdgcn_mfma_f32_16x16x32_bf16(al[i], bh[j], acc[i][j], 0, 0, 0);
                acc[i][j] = __builtin_amdgcn_mfma_f32_16x16x32_bf16(ah[i], bl[j], acc[i][j], 0, 0, 0);
                acc[i][j] = __builtin_amdgcn_mfma_f32_16x16x32_bf16(ah[i], bh[j], acc[i][j], 0, 0, 0);
            }
    }

    #pragma unroll
    for (int j = 0; j < 4; ++j) {
        const int n = n0 + (wc << 6) + (j << 4) + ln;
        #pragma unroll
        for (int i = 0; i < 4; ++i) {
            const int mb = m0 + (wr << 6) + (i << 4) + (quad << 2);
            #pragma unroll
            for (int r = 0; r < 4; ++r) {
                const int m = mb + r;
                float v = acc[i][j][r];
                if (EPI == 0) {
                    C0[(size_t)m * N + n] = v;
                } else {
                    if (n < 512) C0[(size_t)m * 512 + n] = v;
                    else         C1[(size_t)m * 512 + (n - 512)] = v;
                }
            }
        }
    }
}

// ---------------------------------------------------------------------------
// MFMA NT GEMM, bf16x2 split (A single bf16, W hi/lo): attention path.
// EPI 3: v+=bias[n], scatter to out(8,1024,768) as fp32
// EPI 4: v+=bias[n], write bf16 to C (row stride N)
// ---------------------------------------------------------------------------
template<int EPI>
__global__ __launch_bounds__(256) void gemm_mfma2(
    const u16* __restrict__ Ah,
    const u16* __restrict__ Whi, const u16* __restrict__ Wlo,
    const float* __restrict__ bias,
    void* __restrict__ Cv,
    int M, int N, int K)
{
    __shared__ __align__(16) u16 Ash[128 * 40];
    __shared__ __align__(16) u16 Bsh[128 * 40];
    __shared__ __align__(16) u16 Bsl[128 * 40];
    const int t = threadIdx.x;
    const int m0 = blockIdx.y << 7, n0 = blockIdx.x << 7;
    const int lane = t & 63, wave = t >> 6;
    const int wr = wave >> 1, wc = wave & 1;
    const int ln = lane & 15, quad = lane >> 4;

    f32x4 acc[4][4];
    #pragma unroll
    for (int i = 0; i < 4; ++i)
        #pragma unroll
        for (int j = 0; j < 4; ++j) acc[i][j] = (f32x4){0.f, 0.f, 0.f, 0.f};

    const int r0 = t >> 2, sgo = (t & 3) << 3;
    const int r1 = r0 + 64;
    const size_t arow0 = (size_t)(m0 + r0) * K + sgo;
    const size_t arow1 = (size_t)(m0 + r1) * K + sgo;
    const size_t brow0 = (size_t)(n0 + r0) * K + sgo;
    const size_t brow1 = (size_t)(n0 + r1) * K + sgo;
    const int l0 = r0 * 40 + sgo, l1 = r1 * 40 + sgo;

    for (int k0 = 0; k0 < K; k0 += 32) {
        __syncthreads();
        *(uint4*)&Ash[l0] = *(const uint4*)(Ah + arow0 + k0);
        *(uint4*)&Ash[l1] = *(const uint4*)(Ah + arow1 + k0);
        *(uint4*)&Bsh[l0] = *(const uint4*)(Whi + brow0 + k0);
        *(uint4*)&Bsh[l1] = *(const uint4*)(Whi + brow1 + k0);
        *(uint4*)&Bsl[l0] = *(const uint4*)(Wlo + brow0 + k0);
        *(uint4*)&Bsl[l1] = *(const uint4*)(Wlo + brow1 + k0);
        __syncthreads();

        bf16x8 bh[4], bl[4], ah[4];
        #pragma unroll
        for (int j = 0; j < 4; ++j) {
            const int r = ((wc << 6) + (j << 4) + ln) * 40 + (quad << 3);
            bh[j] = *(const bf16x8*)&Bsh[r];
            bl[j] = *(const bf16x8*)&Bsl[r];
        }
        #pragma unroll
        for (int i = 0; i < 4; ++i) {
            const int r = ((wr << 6) + (i << 4) + ln) * 40 + (quad << 3);
            ah[i] = *(const bf16x8*)&Ash[r];
        }
        #pragma unroll
        for (int i = 0; i < 4; ++i)
            #pragma unroll
            for (int j = 0; j < 4; ++j) {
                acc[i][j] = __builtin_amdgcn_mfma_f32_16x16x32_bf16(ah[i], bl[j], acc[i][j], 0, 0, 0);
                acc[i][j] = __builtin_amdgcn_mfma_f32_16x16x32_bf16(ah[i], bh[j], acc[i][j], 0, 0, 0);
            }
    }

    #pragma unroll
    for (int j = 0; j < 4; ++j) {
        const int n = n0 + (wc << 6) + (j << 4) + ln;
        const float bv = bias[n];
        #pragma unroll
        for (int i = 0; i < 4; ++i) {
            const int mb = m0 + (wr << 6) + (i << 4) + (quad << 2);
            #pragma unroll
            for (int r = 0; r < 4; ++r) {
                const int m = mb + r;
                const float v = acc[i][j][r] + bv;
                if (EPI == 4) {
                    ((u16*)Cv)[(size_t)m * N + n] = f2bf(v);
                } else {
                    const int b = m / 3072;
                    const int pos = m - b * 3072;
                    const int seg = pos >> 10;
                    const int l = pos & 1023;
                    ((float*)Cv)[(size_t)((b << 10) + l) * 768 + seg * 256 + n] = v;
                }
            }
        }
    }
}

// ---------------------------------------------------------------------------
// fp32 NT GEMM, used for the skinny x_proj (N=64, K=512)
// ---------------------------------------------------------------------------
__global__ __launch_bounds__(256) void gemm_nt0(
    const float* __restrict__ A, const float* __restrict__ W,
    float* __restrict__ C0, int M, int N, int K)
{
    __shared__ float As[16][64];
    __shared__ float Ws[16][64];
    const int tid = threadIdx.x;
    const int tx = tid & 15;
    const int ty = tid >> 4;
    const int m0 = blockIdx.y * 64;
    const int n0 = blockIdx.x * 64;
    const int lr = tid >> 2;
    const int lk = (tid & 3) << 2;
    const float* Ag = A + (size_t)(m0 + lr) * K + lk;
    const float* Wg = W + (size_t)(n0 + lr) * K + lk;
    float acc[4][4];
    #pragma unroll
    for (int i = 0; i < 4; ++i)
        #pragma unroll
        for (int j = 0; j < 4; ++j) acc[i][j] = 0.f;

    for (int k0 = 0; k0 < K; k0 += 16) {
        float4 a4 = *(const float4*)(Ag + k0);
        float4 w4 = *(const float4*)(Wg + k0);
        __syncthreads();
        As[lk + 0][lr] = a4.x; As[lk + 1][lr] = a4.y;
        As[lk + 2][lr] = a4.z; As[lk + 3][lr] = a4.w;
        Ws[lk + 0][lr] = w4.x; Ws[lk + 1][lr] = w4.y;
        Ws[lk + 2][lr] = w4.z; Ws[lk + 3][lr] = w4.w;
        __syncthreads();
        #pragma unroll
        for (int k = 0; k < 16; ++k) {
            float4 av = *(const float4*)&As[k][ty << 2];
            float4 wv = *(const float4*)&Ws[k][tx << 2];
            float a[4] = {av.x, av.y, av.z, av.w};
            float w[4] = {wv.x, wv.y, wv.z, wv.w};
            #pragma unroll
            for (int i = 0; i < 4; ++i)
                #pragma unroll
                for (int j = 0; j < 4; ++j)
                    acc[i][j] = fmaf(a[i], w[j], acc[i][j]);
        }
    }

    #pragma unroll
    for (int i = 0; i < 4; ++i) {
        const int m = m0 + (ty << 2) + i;
        #pragma unroll
        for (int j = 0; j < 4; ++j) {
            const int n = n0 + (tx << 2) + j;
            C0[(size_t)m * N + n] = acc[i][j];
        }
    }
}

// ---------------------------------------------------------------------------
// K3: depthwise causal conv(4) + bias + SiLU.
// ---------------------------------------------------------------------------
__global__ __launch_bounds__(256) void conv_silu_k(
    const float* __restrict__ xi, const float* __restrict__ cw,
    const float* __restrict__ cb, float* __restrict__ xc)
{
    const size_t idx = (size_t)blockIdx.x * 256 + threadIdx.x;
    const int d = (int)(idx & 511);
    const int l = (int)((idx >> 9) & 1023);
    const float4 w4 = ((const float4*)cw)[d];
    const float* p = xi + idx;
    float s = cb[d];
    s = fmaf((l >= 3 ? p[-3 * 512] : 0.f), w4.x, s);
    s = fmaf((l >= 2 ? p[-2 * 512] : 0.f), w4.y, s);
    s = fmaf((l >= 1 ? p[-1 * 512] : 0.f), w4.z, s);
    s = fmaf(p[0], w4.w, s);
    xc[idx] = s / (1.f + __expf(-s));
}

// ---------------------------------------------------------------------------
// K5: delta = softplus(dbl[:, :16] @ dt_proj_w.T + dt_proj_b)   (dbl stride 64)
// ---------------------------------------------------------------------------
__global__ __launch_bounds__(256) void delta_k(
    const float* __restrict__ dbl, const float* __restrict__ dtw,
    const float* __restrict__ dtb, float* __restrict__ dlt)
{
    const size_t idx = (size_t)blockIdx.x * 256 + threadIdx.x;
    const int d = (int)(idx & 511);
    const size_t row = idx >> 9;
    const float4* dr = (const float4*)(dbl + row * 64);
    const float4* wr = (const float4*)(dtw + (size_t)d * 16);
    float s = dtb[d];
    #pragma unroll
    for (int r = 0; r < 4; ++r) {
        float4 a = dr[r]; float4 b = wr[r];
        s = fmaf(a.x, b.x, s); s = fmaf(a.y, b.y, s);
        s = fmaf(a.z, b.z, s); s = fmaf(a.w, b.w, s);
    }
    dlt[idx] = (s > 20.f) ? s : log1pf(__expf(s));
}

// ---------------------------------------------------------------------------
// Chunked selective scan (3 passes), scan3 fuses gate and writes yg hi/lo
// dbl row stride is 64 (padded): B at +16, C at +32.
// ---------------------------------------------------------------------------
__global__ __launch_bounds__(512) void scan1_k(
    const float* __restrict__ dlt, const float* __restrict__ xc,
    const float* __restrict__ dbl, const float* __restrict__ A_log,
    float* __restrict__ hmid, float* __restrict__ dsums)
{
    __shared__ float Bs[CL][16];
    const int b = blockIdx.x >> 5;
    const int c = blockIdx.x & 31;
    const int d = threadIdx.x;
    const size_t rowbase = (size_t)b * LL + (size_t)c * CL;
    {
        const int l = threadIdx.x >> 4, s = threadIdx.x & 15;
        Bs[l][s] = dbl[(rowbase + l) * 64 + 16 + s];
    }
    __syncthreads();
    float A[16];
    #pragma unroll
    for (int s = 0; s < 16; ++s) A[s] = -__expf(A_log[(size_t)d * 16 + s]);
    float h[16];
    #pragma unroll
    for (int s = 0; s < 16; ++s) h[s] = 0.f;
    float dsum = 0.f;
    #pragma unroll 4
    for (int l = 0; l < CL; ++l) {
        const size_t row = rowbase + l;
        const float dv = dlt[row * DI + d];
        const float uv = xc[row * DI + d];
        const float du = dv * uv;
        dsum += dv;
        #pragma unroll
        for (int s = 0; s < 16; ++s)
            h[s] = fmaf(h[s], __expf(dv * A[s]), du * Bs[l][s]);
    }
    const size_t base = (size_t)(b * CH + c) * 16 * DI + d;
    #pragma unroll
    for (int s = 0; s < 16; ++s) hmid[base + (size_t)s * DI] = h[s];
    dsums[(size_t)(b * CH + c) * DI + d] = dsum;
}

__global__ __launch_bounds__(64) void scan2_k(
    const float* __restrict__ A_log, float* __restrict__ hmid,
    const float* __restrict__ dsums)
{
    const int b = blockIdx.x >> 3;
    const int d = ((blockIdx.x & 7) << 6) + threadIdx.x;
    float A[16];
    #pragma unroll
    for (int s = 0; s < 16; ++s) A[s] = -__expf(A_log[(size_t)d * 16 + s]);
    float h[16];
    #pragma unroll
    for (int s = 0; s < 16; ++s) h[s] = 0.f;

    size_t base = (size_t)(b * CH) * 16 * DI + d;
    float tmp[16];
    #pragma unroll
    for (int s = 0; s < 16; ++s) tmp[s] = hmid[base + (size_t)s * DI];
    float ds = dsums[(size_t)(b * CH) * DI + d];

    for (int c = 0; c < CH; ++c) {
        const int cn = (c + 1 < CH) ? c + 1 : c;
        const size_t nbase = (size_t)(b * CH + cn) * 16 * DI + d;
        float ntmp[16];
        #pragma unroll
        for (int s = 0; s < 16; ++s) ntmp[s] = hmid[nbase + (size_t)s * DI];
        const float nds = dsums[(size_t)(b * CH + cn) * DI + d];
        #pragma unroll
        for (int s = 0; s < 16; ++s) {
            const float hin = h[s];
            hmid[base + (size_t)s * DI] = hin;
            h[s] = fmaf(hin, __expf(A[s] * ds), tmp[s]);
        }
        base = nbase; ds = nds;
        #pragma unroll
        for (int s = 0; s < 16; ++s) tmp[s] = ntmp[s];
    }
}

__global__ __launch_bounds__(512) void scan3_k(
    const float* __restrict__ dlt, const float* __restrict__ xc,
    const float* __restrict__ dbl, const float* __restrict__ zb,
    const float* __restrict__ A_log, const float* __restrict__ Dpp,
    const float* __restrict__ hmid,
    u16* __restrict__ yg_hi, u16* __restrict__ yg_lo)
{
    __shared__ float Bs[CL][16];
    __shared__ float Cs[CL][16];
    const int b = blockIdx.x >> 5;
    const int c = blockIdx.x & 31;
    const int d = threadIdx.x;
    const size_t rowbase = (size_t)b * LL + (size_t)c * CL;
    {
        const int l = threadIdx.x >> 4, s = threadIdx.x & 15;
        Bs[l][s] = dbl[(rowbase + l) * 64 + 16 + s];
        Cs[l][s] = dbl[(rowbase + l) * 64 + 32 + s];
    }
    __syncthreads();
    float A[16];
    #pragma unroll
    for (int s = 0; s < 16; ++s) A[s] = -__expf(A_log[(size_t)d * 16 + s]);
    float h[16];
    const size_t base = (size_t)(b * CH + c) * 16 * DI + d;
    #pragma unroll
    for (int s = 0; s < 16; ++s) h[s] = hmid[base + (size_t)s * DI];
    const float Dpv = Dpp[d];

    #pragma unroll 4
    for (int l = 0; l < CL; ++l) {
        const size_t row = rowbase + l;
        const float dv = dlt[row * DI + d];
        const float uv = xc[row * DI + d];
        const float zv = zb[row * DI + d];
        const float du = dv * uv;
        float y = 0.f;
        #pragma unroll
        for (int s = 0; s < 16; ++s) {
            h[s] = fmaf(h[s], __expf(dv * A[s]), du * Bs[l][s]);
            y = fmaf(h[s], Cs[l][s], y);
        }
        const float sig = 1.f / (1.f + __expf(-zv));
        const float out = (y + uv * Dpv) * (zv * sig);
        u16 hh, ll; splitf(out, hh, ll);
        yg_hi[row * DI + d] = hh;
        yg_lo[row * DI + d] = ll;
    }
}

// ---------------------------------------------------------------------------
// K8: 3x LayerNorm -> hcat (B,3L,256) as single bf16
// ---------------------------------------------------------------------------
__global__ __launch_bounds__(64) void ln_concat_k(
    const float* __restrict__ x, const float* __restrict__ mo,
    const float* __restrict__ angE,
    const float* __restrict__ nw, const float* __restrict__ nb,
    const float* __restrict__ naw, const float* __restrict__ nab,
    const float* __restrict__ ngw, const float* __restrict__ ngb,
    u16* __restrict__ hcat)
{
    const int rowo = blockIdx.x;
    const int b = rowo / 3072;
    const int pos = rowo - b * 3072;
    const int seg = pos >> 10;
    const int l = pos & 1023;
    const size_t srow = (size_t)b * LL + l;
    const float* src; const float* w; const float* bias;
    if (seg == 0)      { src = x    + srow * DM; w = nw;  bias = nb;  }
    else if (seg == 1) { src = mo   + srow * DM; w = naw; bias = nab; }
    else               { src = angE + srow * DM; w = ngw; bias = ngb; }

    const int lane = threadIdx.x;
    float4 v = *(const float4*)(src + lane * 4);
    float s  = v.x + v.y + v.z + v.w;
    float s2 = v.x * v.x + v.y * v.y + v.z * v.z + v.w * v.w;
    #pragma unroll
    for (int off = 32; off > 0; off >>= 1) {
        s  += __shfl_down(s, off);
        s2 += __shfl_down(s2, off);
    }
    s = __shfl(s, 0); s2 = __shfl(s2, 0);
    const float mean = s * (1.f / DM);
    const float var = s2 * (1.f / DM) - mean * mean;
    const float inv = rsqrtf(var + 1e-5f);
    float4 wv = *(const float4*)(w + lane * 4);
    float4 bv = *(const float4*)(bias + lane * 4);
    ushort4 o;
    o.x = f2bf((v.x - mean) * inv * wv.x + bv.x);
    o.y = f2bf((v.y - mean) * inv * wv.y + bv.y);
    o.z = f2bf((v.z - mean) * inv * wv.z + bv.z);
    o.w = f2bf((v.w - mean) * inv * wv.w + bv.w);
    *(ushort4*)(hcat + (size_t)rowo * DM + lane * 4) = o;
}

// ---------------------------------------------------------------------------
// K10: attention over S=8; bf16 qkv in, bf16 atto out
// ---------------------------------------------------------------------------
__global__ __launch_bounds__(64) void attn_k(
    const u16* __restrict__ qkv, u16* __restrict__ atto)
{
    const int n = blockIdx.x;
    const int hd = threadIdx.x >> 3;
    const int s = threadIdx.x & 7;
    const float scale = 0.17677669529663687f;

    float q[32];
    {
        const uint4* qp = (const uint4*)(qkv + ((size_t)(s * 3072 + n)) * 768 + hd * 32);
        #pragma unroll
        for (int i = 0; i < 4; ++i) {
            uint4 t = qp[i];
            unsigned w[4] = {t.x, t.y, t.z, t.w};
            #pragma unroll
            for (int p = 0; p < 4; ++p) {
                union { unsigned u; float f; } a, b;
                a.u = w[p] << 16;          q[i * 8 + p * 2 + 0] = a.f;
                b.u = w[p] & 0xffff0000u;  q[i * 8 + p * 2 + 1] = b.f;
            }
        }
    }
    float sc[8];
    #pragma unroll
    for (int t = 0; t < 8; ++t) {
        const uint4* kp = (const uint4*)(qkv + ((size_t)(t * 3072 + n)) * 768 + 256 + hd * 32);
        float dot = 0.f;
        #pragma unroll
        for (int i = 0; i < 4; ++i) {
            uint4 kv = kp[i];
            unsigned w[4] = {kv.x, kv.y, kv.z, kv.w};
            #pragma unroll
            for (int p = 0; p < 4; ++p) {
                union { unsigned u; float f; } a, b;
                a.u = w[p] << 16;
                b.u = w[p] & 0xffff0000u;
                dot = fmaf(q[i * 8 + p * 2 + 0], a.f, dot);
                dot = fmaf(q[i * 8 + p * 2 + 1], b.f, dot);
            }
        }
        sc[t] = dot * scale;
    }
    float mx = sc[0];
    #pragma unroll
    for (int t = 1; t < 8; ++t) mx = fmaxf(mx, sc[t]);
    float se = 0.f;
    #pragma unroll
    for (int t = 0; t < 8; ++t) { sc[t] = __expf(sc[t] - mx); se += sc[t]; }
    const float inv = 1.f / se;

    float o[32];
    #pragma unroll
    for (int i = 0; i < 32; ++i) o[i] = 0.f;
    #pragma unroll
    for (int t = 0; t < 8; ++t) {
        const uint4* vp = (const uint4*)(qkv + ((size_t)(t * 3072 + n)) * 768 + 512 + hd * 32);
        const float wgt = sc[t] * inv;
        #pragma unroll
        for (int i = 0; i < 4; ++i) {
            uint4 vv = vp[i];
            unsigned w[4] = {vv.x, vv.y, vv.z, vv.w};
            #pragma unroll
            for (int p = 0; p < 4; ++p) {
                union { unsigned u; float f; } a, b;
                a.u = w[p] << 16;
                b.u = w[p] & 0xffff0000u;
                o[i * 8 + p * 2 + 0] = fmaf(wgt, a.f, o[i * 8 + p * 2 + 0]);
                o[i * 8 + p * 2 + 1] = fmaf(wgt, b.f, o[i * 8 + p * 2 + 1]);
            }
        }
    }
    u16* op = atto + ((size_t)(s * 3072 + n)) * 256 + hd * 32;
    #pragma unroll
    for (int g = 0; g < 8; ++g) {
        ushort4 t;
        t.x = f2bf(o[g * 4 + 0]); t.y = f2bf(o[g * 4 + 1]);
        t.z = f2bf(o[g * 4 + 2]); t.w = f2bf(o[g * 4 + 3]);
        *(ushort4*)(op + g * 4) = t;
    }
}

// ---------------------------------------------------------------------------
extern "C" void kernel_launch(void* const* d_in, const int* in_sizes, int n_in,
                              void* d_out, int out_size, void* d_ws, size_t ws_size,
                              hipStream_t stream) {
    const float* x         = (const float*)d_in[0];
    const float* accele    = (const float*)d_in[1];
    const float* angle     = (const float*)d_in[2];
    const float* acc_w     = (const float*)d_in[3];
    const float* acc_b     = (const float*)d_in[4];
    const float* ang_w     = (const float*)d_in[5];
    const float* ang_b     = (const float*)d_in[6];
    const float* in_proj_w = (const float*)d_in[7];
    const float* conv_w    = (const float*)d_in[8];
    const float* conv_b    = (const float*)d_in[9];
    const float* x_proj_w  = (const float*)d_in[10];
    const float* dt_proj_w = (const float*)d_in[11];
    const float* dt_proj_b = (const float*)d_in[12];
    const float* A_log     = (const float*)d_in[13];
    const float* Dp        = (const float*)d_in[14];
    const float* out_proj_w= (const float*)d_in[15];
    const float* norm_w    = (const float*)d_in[16];
    const float* norm_b    = (const float*)d_in[17];
    const float* norm_acc_w= (const float*)d_in[18];
    const float* norm_acc_b= (const float*)d_in[19];
    const float* norm_ang_w= (const float*)d_in[20];
    const float* norm_ang_b= (const float*)d_in[21];
    const float* attn_in_w = (const float*)d_in[22];
    const float* attn_in_b = (const float*)d_in[23];
    const float* attn_out_w= (const float*)d_in[24];
    const float* attn_out_b= (const float*)d_in[25];

    float* ws = (float*)d_ws;
    // workspace layout (float units)
    u16*   accE_hi = (u16*)(ws);                   // [0, 1M)
    u16*   accE_lo = (u16*)(ws + 1048576);         // [1M, 2M)
    float* angE    = ws + 2097152;                 // [2M, 4M)
    float* xi      = ws + 4194304;                 // [4M, 8M)   dead after conv
    float* zb      = ws + 8388608;                 // [8M, 12M)
    float* xc      = ws + 12582912;                // [12M, 16M)
    float* dltb    = ws + 17170432;                // [17.17M, 21.36M)
    u16*   wcv     = (u16*)(ws + 18874368);        // weight hi/lo region (inside dltb)
    float* hmid    = ws + 4194304;                 // alias xi
    float* dsums   = ws + 6291456;                 // alias xi tail
    u16*   yg_hi   = (u16*)(ws + 21364736);        // [21.36M, 23.46M)
    u16*   yg_lo   = (u16*)(ws + 23461888);        // [23.46M, 25.56M)
    float* mo      = ws + 25559040;                // [25.56M, 27.66M) (written step 7)
    u16*   hcat    = (u16*)(ws + 27656192);        // [27.66M, 30.80M)  single bf16
    u16*   atto    = (u16*)(ws + 33947648);        // [33.95M, 37.09M)  single bf16
    // qkvb (bf16): 24576*768 u16 = 9.44M floats, alias [0, 9.44M).
    // Written at step 9; accE/angE/xi(hmid,dsums)/zb-prefix all dead by then.
    u16*   qkvb    = (u16*)ws;
    // dblp (8192x64) + wpad (64x512) live in the mo region (mo written step 7,
    // strictly after all dblp/wpad consumers).
    float* dblp    = ws + 25559040;                // 524,288 floats
    float* wpad    = ws + 26083328;                // 131,072 floats

    // weight hi/lo sub-pointers
    u16* inw_hi = wcv;            u16* inw_lo = wcv + 262144;
    u16* ow_hi  = wcv;            u16* ow_lo  = wcv + 131072;
    u16* aiw_hi = wcv + 262144;   u16* aiw_lo = wcv + 458752;
    u16* aow_hi = wcv + 655360;   u16* aow_lo = wcv + 720896;

    // 0. weight prep
    wconv1_k<<<dim3(1024), dim3(256), 0, stream>>>(in_proj_w, inw_hi, inw_lo);
    wpad_k<<<dim3(128), dim3(256), 0, stream>>>(x_proj_w, wpad);

    // 1. embeds
    embed_k<<<dim3(BB * LL), dim3(256), 0, stream>>>(
        accele, angle, acc_w, acc_b, ang_w, ang_b, accE_hi, accE_lo, angE);

    // 2. in_proj (MFMA x3): xz = accE @ in_proj_w.T -> split xi | z
    gemm_mfma<1><<<dim3(1024 / 128, (BB * LL) / 128), dim3(256), 0, stream>>>(
        accE_hi, accE_lo, inw_hi, inw_lo, xi, zb, BB * LL, 1024, DM);

    // 3. causal depthwise conv + SiLU
    conv_silu_k<<<dim3((BB * LL * DI) / 256), dim3(256), 0, stream>>>(
        xi, conv_w, conv_b, xc);

    // 4. x_proj as fp32 GEMM (N padded 48->64) -> dblp (dt|B|C|pad, stride 64)
    gemm_nt0<<<dim3(1, (BB * LL) / 64), dim3(256), 0, stream>>>(
        xc, wpad, dblp, BB * LL, 64, DI);

    // 5. delta
    delta_k<<<dim3((BB * LL * DI) / 256), dim3(256), 0, stream>>>(
        dblp, dt_proj_w, dt_proj_b, dltb);

    // 6. chunked selective scan + gate -> yg hi/lo
    scan1_k<<<dim3(BB * CH), dim3(512), 0, stream>>>(
        dltb, xc, dblp, A_log, hmid, dsums);
    scan2_k<<<dim3(64), dim3(64), 0, stream>>>(A_log, hmid, dsums);
    scan3_k<<<dim3(BB * CH), dim3(512), 0, stream>>>(
        dltb, xc, dblp, zb, A_log, Dp, hmid, yg_hi, yg_lo);

    // 6.5 remaining weight splits (dltb dead; region safe until step 11)
    wconv2_k<<<dim3(1536), dim3(256), 0, stream>>>(
        out_proj_w, attn_in_w, attn_out_w, wcv);

    // 7. out_proj (MFMA x3) -> mo (overwrites dblp/wpad — both dead now)
    gemm_mfma<0><<<dim3(DM / 128, (BB * LL) / 128), dim3(256), 0, stream>>>(
        yg_hi, yg_lo, ow_hi, ow_lo, mo, nullptr, BB * LL, DM, DI);

    // 8. 3x LayerNorm -> hcat (single bf16)
    ln_concat_k<<<dim3(BB * 3 * LL), dim3(64), 0, stream>>>(
        x, mo, angE, norm_w, norm_b, norm_acc_w, norm_acc_b,
        norm_ang_w, norm_ang_b, hcat);

    // 9. qkv (MFMA x2, +bias) -> qkvb bf16
    gemm_mfma2<4><<<dim3(768 / 128, (BB * 3 * LL) / 128), dim3(256), 0, stream>>>(
        hcat, aiw_hi, aiw_lo, attn_in_b, (void*)qkvb, BB * 3 * LL, 768, DM);

    // 10. attention over S=8 -> atto bf16
    attn_k<<<dim3(3 * LL), dim3(64), 0, stream>>>(qkvb, atto);

    // 11. attn out-proj (MFMA x2, +bias, scatter) -> d_out
    gemm_mfma2<3><<<dim3(DM / 128, (BB * 3 * LL) / 128), dim3(256), 0, stream>>>(
        atto, aow_hi, aow_lo, attn_out_b, d_out, BB * 3 * LL, DM, DM);
}

// Round 6
// 363.475 us; speedup vs baseline: 3.2784x; 1.0051x over previous
//
#include <hip/hip_runtime.h>

// Problem constants
#define BB 8
#define LL 1024
#define DM 256
#define NH 8
#define DI 512
#define DS 16
#define DC 4
#define DR 16

// chunked-scan constants
#define CH 32
#define CL 32

typedef short bf16x8 __attribute__((ext_vector_type(8)));
typedef float f32x4 __attribute__((ext_vector_type(4)));
typedef unsigned short u16;

// split fp32 -> bf16 hi + bf16 lo (x ~= hi + lo, ~16 mantissa bits total)
__device__ __forceinline__ void splitf(float x, u16& h, u16& l) {
    union { float f; unsigned u; } a; a.f = x;
    unsigned r = (a.u + 0x7fffu + ((a.u >> 16) & 1u)) & 0xffff0000u;
    h = (u16)(r >> 16);
    union { unsigned u; float f; } b; b.u = r;
    const float res = x - b.f;
    union { float f; unsigned u; } c; c.f = res;
    l = (u16)((c.u + 0x7fffu + ((c.u >> 16) & 1u)) >> 16);
}

// fp32 -> bf16 round-to-nearest-even
__device__ __forceinline__ u16 f2bf(float x) {
    union { float f; unsigned u; } a; a.f = x;
    return (u16)((a.u + 0x7fffu + ((a.u >> 16) & 1u)) >> 16);
}

// async global->LDS 16B copy: deposits at (wave-uniform base) + lane*16B
__device__ __forceinline__ void gl16(const u16* g, u16* l) {
    __builtin_amdgcn_global_load_lds(
        (const __attribute__((address_space(1))) unsigned int*)g,
        (__attribute__((address_space(3))) unsigned int*)l,
        16, 0, 0);
}

// ---------------------------------------------------------------------------
// prep: all weight conversions in one kernel.
// wcvb layout (u16): inw_hi 0 | inw_lo 262144 | ow_hi 524288 | ow_lo 655360 |
//                    aiw_hi 786432 | aiw_lo 983040 | aow_hi 1179648 | aow_lo 1245184
// ---------------------------------------------------------------------------
__global__ __launch_bounds__(256) void prep_k(
    const float* __restrict__ inw, const float* __restrict__ ow,
    const float* __restrict__ aiw, const float* __restrict__ aow,
    const float* __restrict__ xpw, u16* __restrict__ wcvb,
    float* __restrict__ wpad)
{
    const int i = blockIdx.x * 256 + threadIdx.x;   // < 688128
    if (i < 262144) {
        u16 h, l; splitf(inw[i], h, l);
        wcvb[i] = h; wcvb[262144 + i] = l;
    } else if (i < 393216) {
        const int o = i - 262144;
        u16 h, l; splitf(ow[o], h, l);
        wcvb[524288 + o] = h; wcvb[655360 + o] = l;
    } else if (i < 589824) {
        const int o = i - 393216;
        u16 h, l; splitf(aiw[o], h, l);
        wcvb[786432 + o] = h; wcvb[983040 + o] = l;
    } else if (i < 655360) {
        const int o = i - 589824;
        u16 h, l; splitf(aow[o], h, l);
        wcvb[1179648 + o] = h; wcvb[1245184 + o] = l;
    } else if (i < 688128) {
        const int o = i - 655360;
        wpad[o] = ((o >> 9) < 48) ? xpw[o] : 0.f;   // pad x_proj_w 48->64 rows
    }
}

// ---------------------------------------------------------------------------
// K1: embed -> accE (bf16 hi/lo), angE fp32
// ---------------------------------------------------------------------------
__global__ __launch_bounds__(256) void embed_k(
    const float* __restrict__ accele, const float* __restrict__ angle,
    const float* __restrict__ acc_w, const float* __restrict__ acc_b,
    const float* __restrict__ ang_w, const float* __restrict__ ang_b,
    u16* __restrict__ accE_hi, u16* __restrict__ accE_lo,
    float* __restrict__ angE)
{
    const int row = blockIdx.x;
    const int d = threadIdx.x;
    const float* a_in = accele + (size_t)row * 12;
    const float* g_in = angle + (size_t)row * 12;
    float sa = acc_b[d], sg = ang_b[d];
    #pragma unroll
    for (int j = 0; j < 12; ++j) {
        sa = fmaf(a_in[j], acc_w[d * 12 + j], sa);
        sg = fmaf(g_in[j], ang_w[d * 12 + j], sg);
    }
    u16 h, l; splitf(sa, h, l);
    accE_hi[(size_t)row * DM + d] = h;
    accE_lo[(size_t)row * DM + d] = l;
    angE[(size_t)row * DM + d] = sg;
}

// ---------------------------------------------------------------------------
// MFMA NT GEMM, bf16x3 split (A hi/lo, W hi/lo).  128x128 tile, BK=32,
// 4 waves (2x2 of 64x64), 16x16x32 bf16 MFMA.
// Staging via global_load_lds (16B/lane): LDS rows are 32 elems (64B),
// unpadded; bank conflicts avoided by XOR-swizzling the 16B chunk index
// with (row>>1)&3 (2-way aliasing only, which is free).
// EPI 0: C0[m*N+n]=v   EPI 1: split n<512 -> C0 (xi) | C1 (z)
// ---------------------------------------------------------------------------
template<int EPI>
__global__ __launch_bounds__(256) void gemm_mfma(
    const u16* __restrict__ Ahi, const u16* __restrict__ Alo,
    const u16* __restrict__ Whi, const u16* __restrict__ Wlo,
    float* __restrict__ C0, float* __restrict__ C1,
    int M, int N, int K)
{
    __shared__ __align__(16) u16 Ash[128 * 32];
    __shared__ __align__(16) u16 Asl[128 * 32];
    __shared__ __align__(16) u16 Bsh[128 * 32];
    __shared__ __align__(16) u16 Bsl[128 * 32];
    const int t = threadIdx.x;
    const int m0 = blockIdx.y << 7, n0 = blockIdx.x << 7;
    const int lane = t & 63, wave = t >> 6;
    const int wr = wave >> 1, wc = wave & 1;
    const int ln = lane & 15, quad = lane >> 4;

    f32x4 acc[4][4];
    #pragma unroll
    for (int i = 0; i < 4; ++i)
        #pragma unroll
        for (int j = 0; j < 4; ++j) acc[i][j] = (f32x4){0.f, 0.f, 0.f, 0.f};

    // staging: thread t covers rows sr and sr+64, swizzled chunk cs (16B)
    const int sr = t >> 2;
    const int cs = (t & 3) ^ ((sr >> 1) & 3);   // same for sr and sr+64
    const size_t arow0 = (size_t)(m0 + sr) * K + (cs << 3);
    const size_t arow1 = (size_t)(m0 + sr + 64) * K + (cs << 3);
    const size_t brow0 = (size_t)(n0 + sr) * K + (cs << 3);
    const size_t brow1 = (size_t)(n0 + sr + 64) * K + (cs << 3);
    const int lds_lo = wave << 9;            // wave-uniform: rows wave*16..
    const int lds_hi = 2048 + (wave << 9);   // rows 64+wave*16..

    for (int k0 = 0; k0 < K; k0 += 32) {
        __syncthreads();
        gl16(Ahi + arow0 + k0, &Ash[lds_lo]);
        gl16(Ahi + arow1 + k0, &Ash[lds_hi]);
        gl16(Alo + arow0 + k0, &Asl[lds_lo]);
        gl16(Alo + arow1 + k0, &Asl[lds_hi]);
        gl16(Whi + brow0 + k0, &Bsh[lds_lo]);
        gl16(Whi + brow1 + k0, &Bsh[lds_hi]);
        gl16(Wlo + brow0 + k0, &Bsl[lds_lo]);
        gl16(Wlo + brow1 + k0, &Bsl[lds_hi]);
        __syncthreads();   // drains vmcnt(0): deposits visible

        bf16x8 bh[4], bl[4], ah[4], al[4];
        #pragma unroll
        for (int j = 0; j < 4; ++j) {
            const int rr = (wc << 6) + (j << 4) + ln;
            const int off = (rr << 5) + (((quad ^ (rr >> 1)) & 3) << 3);
            bh[j] = *(const bf16x8*)&Bsh[off];
            bl[j] = *(const bf16x8*)&Bsl[off];
        }
        #pragma unroll
        for (int i = 0; i < 4; ++i) {
            const int rr = (wr << 6) + (i << 4) + ln;
            const int off = (rr << 5) + (((quad ^ (rr >> 1)) & 3) << 3);
            ah[i] = *(const bf16x8*)&Ash[off];
            al[i] = *(const bf16x8*)&Asl[off];
        }
        #pragma unroll
        for (int i = 0; i < 4; ++i)
            #pragma unroll
            for (int j = 0; j < 4; ++j) {
                acc[i][j] = __builtin_amdgcn_mfma_f32_16x16x32_bf16(al[i], bh[j], acc[i][j], 0, 0, 0);
                acc[i][j] = __builtin_amdgcn_mfma_f32_16x16x32_bf16(ah[i], bl[j], acc[i][j], 0, 0, 0);
                acc[i][j] = __builtin_amdgcn_mfma_f32_16x16x32_bf16(ah[i], bh[j], acc[i][j], 0, 0, 0);
            }
    }

    // epilogue: C/D layout col=lane&15, row=quad*4+reg
    #pragma unroll
    for (int j = 0; j < 4; ++j) {
        const int n = n0 + (wc << 6) + (j << 4) + ln;
        #pragma unroll
        for (int i = 0; i < 4; ++i) {
            const int mb = m0 + (wr << 6) + (i << 4) + (quad << 2);
            #pragma unroll
            for (int r = 0; r < 4; ++r) {
                const int m = mb + r;
                float v = acc[i][j][r];
                if (EPI == 0) {
                    C0[(size_t)m * N + n] = v;
                } else {
                    if (n < 512) C0[(size_t)m * 512 + n] = v;
                    else         C1[(size_t)m * 512 + (n - 512)] = v;
                }
            }
        }
    }
}

// ---------------------------------------------------------------------------
// MFMA NT GEMM, bf16x2 split (A single bf16, W hi/lo): attention path.
// Same global_load_lds + swizzle staging.
// EPI 3: v+=bias[n], scatter to out(8,1024,768) fp32
// EPI 4: v+=bias[n], write bf16 (row stride N)
// ---------------------------------------------------------------------------
template<int EPI>
__global__ __launch_bounds__(256) void gemm_mfma2(
    const u16* __restrict__ Ah,
    const u16* __restrict__ Whi, const u16* __restrict__ Wlo,
    const float* __restrict__ bias,
    void* __restrict__ Cv,
    int M, int N, int K)
{
    __shared__ __align__(16) u16 Ash[128 * 32];
    __shared__ __align__(16) u16 Bsh[128 * 32];
    __shared__ __align__(16) u16 Bsl[128 * 32];
    const int t = threadIdx.x;
    const int m0 = blockIdx.y << 7, n0 = blockIdx.x << 7;
    const int lane = t & 63, wave = t >> 6;
    const int wr = wave >> 1, wc = wave & 1;
    const int ln = lane & 15, quad = lane >> 4;

    f32x4 acc[4][4];
    #pragma unroll
    for (int i = 0; i < 4; ++i)
        #pragma unroll
        for (int j = 0; j < 4; ++j) acc[i][j] = (f32x4){0.f, 0.f, 0.f, 0.f};

    const int sr = t >> 2;
    const int cs = (t & 3) ^ ((sr >> 1) & 3);
    const size_t arow0 = (size_t)(m0 + sr) * K + (cs << 3);
    const size_t arow1 = (size_t)(m0 + sr + 64) * K + (cs << 3);
    const size_t brow0 = (size_t)(n0 + sr) * K + (cs << 3);
    const size_t brow1 = (size_t)(n0 + sr + 64) * K + (cs << 3);
    const int lds_lo = wave << 9;
    const int lds_hi = 2048 + (wave << 9);

    for (int k0 = 0; k0 < K; k0 += 32) {
        __syncthreads();
        gl16(Ah  + arow0 + k0, &Ash[lds_lo]);
        gl16(Ah  + arow1 + k0, &Ash[lds_hi]);
        gl16(Whi + brow0 + k0, &Bsh[lds_lo]);
        gl16(Whi + brow1 + k0, &Bsh[lds_hi]);
        gl16(Wlo + brow0 + k0, &Bsl[lds_lo]);
        gl16(Wlo + brow1 + k0, &Bsl[lds_hi]);
        __syncthreads();

        bf16x8 bh[4], bl[4], ah[4];
        #pragma unroll
        for (int j = 0; j < 4; ++j) {
            const int rr = (wc << 6) + (j << 4) + ln;
            const int off = (rr << 5) + (((quad ^ (rr >> 1)) & 3) << 3);
            bh[j] = *(const bf16x8*)&Bsh[off];
            bl[j] = *(const bf16x8*)&Bsl[off];
        }
        #pragma unroll
        for (int i = 0; i < 4; ++i) {
            const int rr = (wr << 6) + (i << 4) + ln;
            const int off = (rr << 5) + (((quad ^ (rr >> 1)) & 3) << 3);
            ah[i] = *(const bf16x8*)&Ash[off];
        }
        #pragma unroll
        for (int i = 0; i < 4; ++i)
            #pragma unroll
            for (int j = 0; j < 4; ++j) {
                acc[i][j] = __builtin_amdgcn_mfma_f32_16x16x32_bf16(ah[i], bl[j], acc[i][j], 0, 0, 0);
                acc[i][j] = __builtin_amdgcn_mfma_f32_16x16x32_bf16(ah[i], bh[j], acc[i][j], 0, 0, 0);
            }
    }

    #pragma unroll
    for (int j = 0; j < 4; ++j) {
        const int n = n0 + (wc << 6) + (j << 4) + ln;
        const float bv = bias[n];
        #pragma unroll
        for (int i = 0; i < 4; ++i) {
            const int mb = m0 + (wr << 6) + (i << 4) + (quad << 2);
            #pragma unroll
            for (int r = 0; r < 4; ++r) {
                const int m = mb + r;
                const float v = acc[i][j][r] + bv;
                if (EPI == 4) {
                    ((u16*)Cv)[(size_t)m * N + n] = f2bf(v);
                } else {
                    const int b = m / 3072;
                    const int pos = m - b * 3072;
                    const int seg = pos >> 10;
                    const int l = pos & 1023;
                    ((float*)Cv)[(size_t)((b << 10) + l) * 768 + seg * 256 + n] = v;
                }
            }
        }
    }
}

// ---------------------------------------------------------------------------
// fp32 NT GEMM, used for the skinny x_proj (N=64, K=512)
// ---------------------------------------------------------------------------
__global__ __launch_bounds__(256) void gemm_nt0(
    const float* __restrict__ A, const float* __restrict__ W,
    float* __restrict__ C0, int M, int N, int K)
{
    __shared__ float As[16][64];
    __shared__ float Ws[16][64];
    const int tid = threadIdx.x;
    const int tx = tid & 15;
    const int ty = tid >> 4;
    const int m0 = blockIdx.y * 64;
    const int n0 = blockIdx.x * 64;
    const int lr = tid >> 2;
    const int lk = (tid & 3) << 2;
    const float* Ag = A + (size_t)(m0 + lr) * K + lk;
    const float* Wg = W + (size_t)(n0 + lr) * K + lk;
    float acc[4][4];
    #pragma unroll
    for (int i = 0; i < 4; ++i)
        #pragma unroll
        for (int j = 0; j < 4; ++j) acc[i][j] = 0.f;

    for (int k0 = 0; k0 < K; k0 += 16) {
        float4 a4 = *(const float4*)(Ag + k0);
        float4 w4 = *(const float4*)(Wg + k0);
        __syncthreads();
        As[lk + 0][lr] = a4.x; As[lk + 1][lr] = a4.y;
        As[lk + 2][lr] = a4.z; As[lk + 3][lr] = a4.w;
        Ws[lk + 0][lr] = w4.x; Ws[lk + 1][lr] = w4.y;
        Ws[lk + 2][lr] = w4.z; Ws[lk + 3][lr] = w4.w;
        __syncthreads();
        #pragma unroll
        for (int k = 0; k < 16; ++k) {
            float4 av = *(const float4*)&As[k][ty << 2];
            float4 wv = *(const float4*)&Ws[k][tx << 2];
            float a[4] = {av.x, av.y, av.z, av.w};
            float w[4] = {wv.x, wv.y, wv.z, wv.w};
            #pragma unroll
            for (int i = 0; i < 4; ++i)
                #pragma unroll
                for (int j = 0; j < 4; ++j)
                    acc[i][j] = fmaf(a[i], w[j], acc[i][j]);
        }
    }

    #pragma unroll
    for (int i = 0; i < 4; ++i) {
        const int m = m0 + (ty << 2) + i;
        #pragma unroll
        for (int j = 0; j < 4; ++j) {
            const int n = n0 + (tx << 2) + j;
            C0[(size_t)m * N + n] = acc[i][j];
        }
    }
}

// ---------------------------------------------------------------------------
// K3: depthwise causal conv(4) + bias + SiLU.
// ---------------------------------------------------------------------------
__global__ __launch_bounds__(256) void conv_silu_k(
    const float* __restrict__ xi, const float* __restrict__ cw,
    const float* __restrict__ cb, float* __restrict__ xc)
{
    const size_t idx = (size_t)blockIdx.x * 256 + threadIdx.x;
    const int d = (int)(idx & 511);
    const int l = (int)((idx >> 9) & 1023);
    const float4 w4 = ((const float4*)cw)[d];
    const float* p = xi + idx;
    float s = cb[d];
    s = fmaf((l >= 3 ? p[-3 * 512] : 0.f), w4.x, s);
    s = fmaf((l >= 2 ? p[-2 * 512] : 0.f), w4.y, s);
    s = fmaf((l >= 1 ? p[-1 * 512] : 0.f), w4.z, s);
    s = fmaf(p[0], w4.w, s);
    xc[idx] = s / (1.f + __expf(-s));
}

// ---------------------------------------------------------------------------
// Chunked selective scan, delta fused (softplus inline; identical fp32 order).
// dbl row stride 64 (padded): dt at +0, B at +16, C at +32.
// scan1: per (b,d,chunk): scan chunk from h=0 -> h_local[16], dsum
// scan2: sequential prefix over chunks -> h_in (in place)
// scan3: rescan from h_in, fuse gate, write yg hi/lo
// ---------------------------------------------------------------------------
__global__ __launch_bounds__(512) void scan1_k(
    const float* __restrict__ xc, const float* __restrict__ dbl,
    const float* __restrict__ A_log,
    const float* __restrict__ dtw, const float* __restrict__ dtb,
    float* __restrict__ hmid, float* __restrict__ dsums)
{
    __shared__ float Dts[CL][16];
    __shared__ float Bs[CL][16];
    const int b = blockIdx.x >> 5;
    const int c = blockIdx.x & 31;
    const int d = threadIdx.x;
    const size_t rowbase = (size_t)b * LL + (size_t)c * CL;
    {
        const int l = threadIdx.x >> 4, s = threadIdx.x & 15;
        Dts[l][s] = dbl[(rowbase + l) * 64 + s];
        Bs[l][s]  = dbl[(rowbase + l) * 64 + 16 + s];
    }
    __syncthreads();
    float A[16], wdt[16];
    #pragma unroll
    for (int s = 0; s < 16; ++s) A[s] = -__expf(A_log[(size_t)d * 16 + s]);
    #pragma unroll
    for (int s = 0; s < 16; ++s) wdt[s] = dtw[(size_t)d * 16 + s];
    const float dtbd = dtb[d];
    float h[16];
    #pragma unroll
    for (int s = 0; s < 16; ++s) h[s] = 0.f;
    float dsum = 0.f;
    #pragma unroll 4
    for (int l = 0; l < CL; ++l) {
        const size_t row = rowbase + l;
        float sdt = dtbd;
        #pragma unroll
        for (int s = 0; s < 16; ++s) sdt = fmaf(Dts[l][s], wdt[s], sdt);
        const float dv = (sdt > 20.f) ? sdt : log1pf(__expf(sdt));
        const float uv = xc[row * DI + d];
        const float du = dv * uv;
        dsum += dv;
        #pragma unroll
        for (int s = 0; s < 16; ++s)
            h[s] = fmaf(h[s], __expf(dv * A[s]), du * Bs[l][s]);
    }
    const size_t base = (size_t)(b * CH + c) * 16 * DI + d;
    #pragma unroll
    for (int s = 0; s < 16; ++s) hmid[base + (size_t)s * DI] = h[s];
    dsums[(size_t)(b * CH + c) * DI + d] = dsum;
}

__global__ __launch_bounds__(64) void scan2_k(
    const float* __restrict__ A_log, float* __restrict__ hmid,
    const float* __restrict__ dsums)
{
    const int b = blockIdx.x >> 3;
    const int d = ((blockIdx.x & 7) << 6) + threadIdx.x;
    float A[16];
    #pragma unroll
    for (int s = 0; s < 16; ++s) A[s] = -__expf(A_log[(size_t)d * 16 + s]);
    float h[16];
    #pragma unroll
    for (int s = 0; s < 16; ++s) h[s] = 0.f;

    size_t base = (size_t)(b * CH) * 16 * DI + d;
    float tmp[16];
    #pragma unroll
    for (int s = 0; s < 16; ++s) tmp[s] = hmid[base + (size_t)s * DI];
    float ds = dsums[(size_t)(b * CH) * DI + d];

    for (int c = 0; c < CH; ++c) {
        const int cn = (c + 1 < CH) ? c + 1 : c;
        const size_t nbase = (size_t)(b * CH + cn) * 16 * DI + d;
        float ntmp[16];
        #pragma unroll
        for (int s = 0; s < 16; ++s) ntmp[s] = hmid[nbase + (size_t)s * DI];
        const float nds = dsums[(size_t)(b * CH + cn) * DI + d];
        #pragma unroll
        for (int s = 0; s < 16; ++s) {
            const float hin = h[s];
            hmid[base + (size_t)s * DI] = hin;
            h[s] = fmaf(hin, __expf(A[s] * ds), tmp[s]);
        }
        base = nbase; ds = nds;
        #pragma unroll
        for (int s = 0; s < 16; ++s) tmp[s] = ntmp[s];
    }
}

__global__ __launch_bounds__(512) void scan3_k(
    const float* __restrict__ xc, const float* __restrict__ dbl,
    const float* __restrict__ zb, const float* __restrict__ A_log,
    const float* __restrict__ dtw, const float* __restrict__ dtb,
    const float* __restrict__ Dpp, const float* __restrict__ hmid,
    u16* __restrict__ yg_hi, u16* __restrict__ yg_lo)
{
    __shared__ float Dts[CL][16];
    __shared__ float Bs[CL][16];
    __shared__ float Cs[CL][16];
    const int b = blockIdx.x >> 5;
    const int c = blockIdx.x & 31;
    const int d = threadIdx.x;
    const size_t rowbase = (size_t)b * LL + (size_t)c * CL;
    {
        const int l = threadIdx.x >> 4, s = threadIdx.x & 15;
        Dts[l][s] = dbl[(rowbase + l) * 64 + s];
        Bs[l][s]  = dbl[(rowbase + l) * 64 + 16 + s];
        Cs[l][s]  = dbl[(rowbase + l) * 64 + 32 + s];
    }
    __syncthreads();
    float A[16], wdt[16];
    #pragma unroll
    for (int s = 0; s < 16; ++s) A[s] = -__expf(A_log[(size_t)d * 16 + s]);
    #pragma unroll
    for (int s = 0; s < 16; ++s) wdt[s] = dtw[(size_t)d * 16 + s];
    const float dtbd = dtb[d];
    float h[16];
    const size_t base = (size_t)(b * CH + c) * 16 * DI + d;
    #pragma unroll
    for (int s = 0; s < 16; ++s) h[s] = hmid[base + (size_t)s * DI];
    const float Dpv = Dpp[d];

    #pragma unroll 4
    for (int l = 0; l < CL; ++l) {
        const size_t row = rowbase + l;
        float sdt = dtbd;
        #pragma unroll
        for (int s = 0; s < 16; ++s) sdt = fmaf(Dts[l][s], wdt[s], sdt);
        const float dv = (sdt > 20.f) ? sdt : log1pf(__expf(sdt));
        const float uv = xc[row * DI + d];
        const float zv = zb[row * DI + d];
        const float du = dv * uv;
        float y = 0.f;
        #pragma unroll
        for (int s = 0; s < 16; ++s) {
            h[s] = fmaf(h[s], __expf(dv * A[s]), du * Bs[l][s]);
            y = fmaf(h[s], Cs[l][s], y);
        }
        const float sig = 1.f / (1.f + __expf(-zv));
        const float out = (y + uv * Dpv) * (zv * sig);
        u16 hh, ll; splitf(out, hh, ll);
        yg_hi[row * DI + d] = hh;
        yg_lo[row * DI + d] = ll;
    }
}

// ---------------------------------------------------------------------------
// K8: 3x LayerNorm -> hcat (B,3L,256) as single bf16
// ---------------------------------------------------------------------------
__global__ __launch_bounds__(64) void ln_concat_k(
    const float* __restrict__ x, const float* __restrict__ mo,
    const float* __restrict__ angE,
    const float* __restrict__ nw, const float* __restrict__ nb,
    const float* __restrict__ naw, const float* __restrict__ nab,
    const float* __restrict__ ngw, const float* __restrict__ ngb,
    u16* __restrict__ hcat)
{
    const int rowo = blockIdx.x;
    const int b = rowo / 3072;
    const int pos = rowo - b * 3072;
    const int seg = pos >> 10;
    const int l = pos & 1023;
    const size_t srow = (size_t)b * LL + l;
    const float* src; const float* w; const float* bias;
    if (seg == 0)      { src = x    + srow * DM; w = nw;  bias = nb;  }
    else if (seg == 1) { src = mo   + srow * DM; w = naw; bias = nab; }
    else               { src = angE + srow * DM; w = ngw; bias = ngb; }

    const int lane = threadIdx.x;
    float4 v = *(const float4*)(src + lane * 4);
    float s  = v.x + v.y + v.z + v.w;
    float s2 = v.x * v.x + v.y * v.y + v.z * v.z + v.w * v.w;
    #pragma unroll
    for (int off = 32; off > 0; off >>= 1) {
        s  += __shfl_down(s, off);
        s2 += __shfl_down(s2, off);
    }
    s = __shfl(s, 0); s2 = __shfl(s2, 0);
    const float mean = s * (1.f / DM);
    const float var = s2 * (1.f / DM) - mean * mean;
    const float inv = rsqrtf(var + 1e-5f);
    float4 wv = *(const float4*)(w + lane * 4);
    float4 bv = *(const float4*)(bias + lane * 4);
    ushort4 o;
    o.x = f2bf((v.x - mean) * inv * wv.x + bv.x);
    o.y = f2bf((v.y - mean) * inv * wv.y + bv.y);
    o.z = f2bf((v.z - mean) * inv * wv.z + bv.z);
    o.w = f2bf((v.w - mean) * inv * wv.w + bv.w);
    *(ushort4*)(hcat + (size_t)rowo * DM + lane * 4) = o;
}

// ---------------------------------------------------------------------------
// K10: attention over S=8; bf16 qkv in, bf16 atto out
// ---------------------------------------------------------------------------
__global__ __launch_bounds__(64) void attn_k(
    const u16* __restrict__ qkv, u16* __restrict__ atto)
{
    const int n = blockIdx.x;
    const int hd = threadIdx.x >> 3;
    const int s = threadIdx.x & 7;
    const float scale = 0.17677669529663687f;

    float q[32];
    {
        const uint4* qp = (const uint4*)(qkv + ((size_t)(s * 3072 + n)) * 768 + hd * 32);
        #pragma unroll
        for (int i = 0; i < 4; ++i) {
            uint4 t = qp[i];
            unsigned w[4] = {t.x, t.y, t.z, t.w};
            #pragma unroll
            for (int p = 0; p < 4; ++p) {
                union { unsigned u; float f; } a, b;
                a.u = w[p] << 16;          q[i * 8 + p * 2 + 0] = a.f;
                b.u = w[p] & 0xffff0000u;  q[i * 8 + p * 2 + 1] = b.f;
            }
        }
    }
    float sc[8];
    #pragma unroll
    for (int t = 0; t < 8; ++t) {
        const uint4* kp = (const uint4*)(qkv + ((size_t)(t * 3072 + n)) * 768 + 256 + hd * 32);
        float dot = 0.f;
        #pragma unroll
        for (int i = 0; i < 4; ++i) {
            uint4 kv = kp[i];
            unsigned w[4] = {kv.x, kv.y, kv.z, kv.w};
            #pragma unroll
            for (int p = 0; p < 4; ++p) {
                union { unsigned u; float f; } a, b;
                a.u = w[p] << 16;
                b.u = w[p] & 0xffff0000u;
                dot = fmaf(q[i * 8 + p * 2 + 0], a.f, dot);
                dot = fmaf(q[i * 8 + p * 2 + 1], b.f, dot);
            }
        }
        sc[t] = dot * scale;
    }
    float mx = sc[0];
    #pragma unroll
    for (int t = 1; t < 8; ++t) mx = fmaxf(mx, sc[t]);
    float se = 0.f;
    #pragma unroll
    for (int t = 0; t < 8; ++t) { sc[t] = __expf(sc[t] - mx); se += sc[t]; }
    const float inv = 1.f / se;

    float o[32];
    #pragma unroll
    for (int i = 0; i < 32; ++i) o[i] = 0.f;
    #pragma unroll
    for (int t = 0; t < 8; ++t) {
        const uint4* vp = (const uint4*)(qkv + ((size_t)(t * 3072 + n)) * 768 + 512 + hd * 32);
        const float wgt = sc[t] * inv;
        #pragma unroll
        for (int i = 0; i < 4; ++i) {
            uint4 vv = vp[i];
            unsigned w[4] = {vv.x, vv.y, vv.z, vv.w};
            #pragma unroll
            for (int p = 0; p < 4; ++p) {
                union { unsigned u; float f; } a, b;
                a.u = w[p] << 16;
                b.u = w[p] & 0xffff0000u;
                o[i * 8 + p * 2 + 0] = fmaf(wgt, a.f, o[i * 8 + p * 2 + 0]);
                o[i * 8 + p * 2 + 1] = fmaf(wgt, b.f, o[i * 8 + p * 2 + 1]);
            }
        }
    }
    u16* op = atto + ((size_t)(s * 3072 + n)) * 256 + hd * 32;
    #pragma unroll
    for (int g = 0; g < 8; ++g) {
        ushort4 t;
        t.x = f2bf(o[g * 4 + 0]); t.y = f2bf(o[g * 4 + 1]);
        t.z = f2bf(o[g * 4 + 2]); t.w = f2bf(o[g * 4 + 3]);
        *(ushort4*)(op + g * 4) = t;
    }
}

// ---------------------------------------------------------------------------
extern "C" void kernel_launch(void* const* d_in, const int* in_sizes, int n_in,
                              void* d_out, int out_size, void* d_ws, size_t ws_size,
                              hipStream_t stream) {
    const float* x         = (const float*)d_in[0];
    const float* accele    = (const float*)d_in[1];
    const float* angle     = (const float*)d_in[2];
    const float* acc_w     = (const float*)d_in[3];
    const float* acc_b     = (const float*)d_in[4];
    const float* ang_w     = (const float*)d_in[5];
    const float* ang_b     = (const float*)d_in[6];
    const float* in_proj_w = (const float*)d_in[7];
    const float* conv_w    = (const float*)d_in[8];
    const float* conv_b    = (const float*)d_in[9];
    const float* x_proj_w  = (const float*)d_in[10];
    const float* dt_proj_w = (const float*)d_in[11];
    const float* dt_proj_b = (const float*)d_in[12];
    const float* A_log     = (const float*)d_in[13];
    const float* Dp        = (const float*)d_in[14];
    const float* out_proj_w= (const float*)d_in[15];
    const float* norm_w    = (const float*)d_in[16];
    const float* norm_b    = (const float*)d_in[17];
    const float* norm_acc_w= (const float*)d_in[18];
    const float* norm_acc_b= (const float*)d_in[19];
    const float* norm_ang_w= (const float*)d_in[20];
    const float* norm_ang_b= (const float*)d_in[21];
    const float* attn_in_w = (const float*)d_in[22];
    const float* attn_in_b = (const float*)d_in[23];
    const float* attn_out_w= (const float*)d_in[24];
    const float* attn_out_b= (const float*)d_in[25];

    float* ws = (float*)d_ws;
    // workspace layout (float units)
    u16*   accE_hi = (u16*)(ws);                   // [0, 1M)
    u16*   accE_lo = (u16*)(ws + 1048576);         // [1M, 2M)
    float* angE    = ws + 2097152;                 // [2M, 4M)
    float* xi      = ws + 4194304;                 // [4M, 8M)   dead after conv
    float* zb      = ws + 8388608;                 // [8M, 12M)
    float* xc      = ws + 12582912;                // [12M, 16M)
    u16*   wcvb    = (u16*)(ws + 17170432);        // weights hi/lo: 1.31M u16 (former dltb, free)
    float* hmid    = ws + 4194304;                 // alias xi
    float* dsums   = ws + 6291456;                 // alias xi tail
    u16*   yg_hi   = (u16*)(ws + 21364736);        // [21.36M, 23.46M)
    u16*   yg_lo   = (u16*)(ws + 23461888);        // [23.46M, 25.56M)
    float* mo      = ws + 25559040;                // [25.56M, 27.66M) (written step 7)
    u16*   hcat    = (u16*)(ws + 27656192);        // [27.66M, 30.80M)  single bf16
    u16*   atto    = (u16*)(ws + 33947648);        // [33.95M, 37.09M)  single bf16
    u16*   qkvb    = (u16*)ws;                     // alias [0, 9.44M): mamba bufs dead by step 9
    // dblp (8192x64) + wpad (64x512) in the mo region (consumed before step 7)
    float* dblp    = ws + 25559040;                // 524,288 floats
    float* wpad    = ws + 26083328;                // 131,072 floats

    // weight hi/lo sub-pointers (all coexist; no clobber timeline needed)
    u16* inw_hi = wcvb;            u16* inw_lo = wcvb + 262144;
    u16* ow_hi  = wcvb + 524288;   u16* ow_lo  = wcvb + 655360;
    u16* aiw_hi = wcvb + 786432;   u16* aiw_lo = wcvb + 983040;
    u16* aow_hi = wcvb + 1179648;  u16* aow_lo = wcvb + 1245184;

    // 0. all weight prep in one kernel
    prep_k<<<dim3(2688), dim3(256), 0, stream>>>(
        in_proj_w, out_proj_w, attn_in_w, attn_out_w, x_proj_w, wcvb, wpad);

    // 1. embeds
    embed_k<<<dim3(BB * LL), dim3(256), 0, stream>>>(
        accele, angle, acc_w, acc_b, ang_w, ang_b, accE_hi, accE_lo, angE);

    // 2. in_proj (MFMA x3): xz = accE @ in_proj_w.T -> split xi | z
    gemm_mfma<1><<<dim3(1024 / 128, (BB * LL) / 128), dim3(256), 0, stream>>>(
        accE_hi, accE_lo, inw_hi, inw_lo, xi, zb, BB * LL, 1024, DM);

    // 3. causal depthwise conv + SiLU
    conv_silu_k<<<dim3((BB * LL * DI) / 256), dim3(256), 0, stream>>>(
        xi, conv_w, conv_b, xc);

    // 4. x_proj as fp32 GEMM (N padded 48->64) -> dblp (dt|B|C|pad, stride 64)
    gemm_nt0<<<dim3(1, (BB * LL) / 64), dim3(256), 0, stream>>>(
        xc, wpad, dblp, BB * LL, 64, DI);

    // 5+6. chunked selective scan with fused delta + gate -> yg hi/lo
    scan1_k<<<dim3(BB * CH), dim3(512), 0, stream>>>(
        xc, dblp, A_log, dt_proj_w, dt_proj_b, hmid, dsums);
    scan2_k<<<dim3(64), dim3(64), 0, stream>>>(A_log, hmid, dsums);
    scan3_k<<<dim3(BB * CH), dim3(512), 0, stream>>>(
        xc, dblp, zb, A_log, dt_proj_w, dt_proj_b, Dp, hmid, yg_hi, yg_lo);

    // 7. out_proj (MFMA x3) -> mo (overwrites dblp/wpad — both dead now)
    gemm_mfma<0><<<dim3(DM / 128, (BB * LL) / 128), dim3(256), 0, stream>>>(
        yg_hi, yg_lo, ow_hi, ow_lo, mo, nullptr, BB * LL, DM, DI);

    // 8. 3x LayerNorm -> hcat (single bf16)
    ln_concat_k<<<dim3(BB * 3 * LL), dim3(64), 0, stream>>>(
        x, mo, angE, norm_w, norm_b, norm_acc_w, norm_acc_b,
        norm_ang_w, norm_ang_b, hcat);

    // 9. qkv (MFMA x2, +bias) -> qkvb bf16
    gemm_mfma2<4><<<dim3(768 / 128, (BB * 3 * LL) / 128), dim3(256), 0, stream>>>(
        hcat, aiw_hi, aiw_lo, attn_in_b, (void*)qkvb, BB * 3 * LL, 768, DM);

    // 10. attention over S=8 -> atto bf16
    attn_k<<<dim3(3 * LL), dim3(64), 0, stream>>>(qkvb, atto);

    // 11. attn out-proj (MFMA x2, +bias, scatter) -> d_out
    gemm_mfma2<3><<<dim3(DM / 128, (BB * 3 * LL) / 128), dim3(256), 0, stream>>>(
        atto, aow_hi, aow_lo, attn_out_b, d_out, BB * 3 * LL, DM, DM);
}